// Round 1
// baseline (828.007 us; speedup 1.0000x reference)
//
#include <hip/hip_runtime.h>
#include <math.h>

#define BATCH 4
#define SEQ 1024
#define DMODEL 768
#define NHEADS 12
#define HDIM 64
#define D3 2304
#define BH 48            // BATCH*NHEADS
#define NTOK 4096        // BATCH*SEQ
#define NN (SEQ*SEQ)     // 1048576
#define KTH 104857u      // int(1024*1024*0.1)

// ---------------- init: zero histograms, reset select state ----------------
__global__ void k_init(unsigned* __restrict__ hist, unsigned* __restrict__ prefix,
                       unsigned* __restrict__ krem) {
    int t = blockIdx.x * 256 + threadIdx.x;
    if (t < BH * 256) hist[t] = 0u;
    if (t < BH) { prefix[t] = 0u; krem[t] = KTH; }
}

// ---------------- generic fp32 tiled GEMM + bias: C = A@B + bias ----------------
// A[M,K] row-major, B[K,N] row-major, bias[N]. BM=BN=64, BK=16, 256 thr, 4x4 micro.
__global__ __launch_bounds__(256) void k_gemm_bias(
    const float* __restrict__ A, const float* __restrict__ Bm,
    const float* __restrict__ bias, float* __restrict__ C,
    int M, int N, int K) {
    __shared__ float As[16][64];   // [kk][row]
    __shared__ float Bs[16][64];   // [kk][col]
    int tid = threadIdx.x;
    int tx = tid & 15, ty = tid >> 4;
    int row0 = blockIdx.y * 64, col0 = blockIdx.x * 64;
    int arow = tid >> 2;            // 0..63
    int acol = (tid & 3) * 4;       // 0,4,8,12
    int brow = tid >> 4;            // 0..15
    int bcol = (tid & 15) * 4;      // 0..60
    float acc[4][4] = {};
    for (int k0 = 0; k0 < K; k0 += 16) {
        float4 av = *(const float4*)(A + (size_t)(row0 + arow) * K + k0 + acol);
        float4 bv = *(const float4*)(Bm + (size_t)(k0 + brow) * N + col0 + bcol);
        __syncthreads();
        As[acol + 0][arow] = av.x; As[acol + 1][arow] = av.y;
        As[acol + 2][arow] = av.z; As[acol + 3][arow] = av.w;
        *(float4*)&Bs[brow][bcol] = bv;
        __syncthreads();
#pragma unroll
        for (int kk = 0; kk < 16; kk++) {
            float4 a = *(float4*)&As[kk][ty * 4];
            float4 b = *(float4*)&Bs[kk][tx * 4];
            float ar[4] = {a.x, a.y, a.z, a.w};
            float br[4] = {b.x, b.y, b.z, b.w};
#pragma unroll
            for (int r = 0; r < 4; r++)
#pragma unroll
                for (int c = 0; c < 4; c++)
                    acc[r][c] += ar[r] * br[c];
        }
    }
#pragma unroll
    for (int r = 0; r < 4; r++) {
        int row = row0 + ty * 4 + r;
        int col = col0 + tx * 4;
        float4 o;
        o.x = acc[r][0] + bias[col + 0];
        o.y = acc[r][1] + bias[col + 1];
        o.z = acc[r][2] + bias[col + 2];
        o.w = acc[r][3] + bias[col + 3];
        *(float4*)(C + (size_t)row * N + col) = o;
    }
}

// ---------------- scores: S[bh,i,j] = (q_i . k_j) / 8 ----------------
__global__ __launch_bounds__(256) void k_scores(const float* __restrict__ qkv,
                                                float* __restrict__ S) {
    int bh = blockIdx.z;
    int b = bh / NHEADS, h = bh % NHEADS;
    int i0 = blockIdx.y * 64, j0 = blockIdx.x * 64;
    __shared__ float Qs[64][64];   // [kk][i]
    __shared__ float Ks[64][64];   // [kk][j]
    int tid = threadIdx.x;
    int li = tid >> 2;             // 0..63
    int kb = (tid & 3) * 16;       // 0,16,32,48
    const float* qbase = qkv + (size_t)(b * SEQ + i0) * D3 + h * HDIM;
    const float* kbase = qkv + (size_t)(b * SEQ + j0) * D3 + DMODEL + h * HDIM;
#pragma unroll
    for (int u = 0; u < 4; u++) {
        float4 qv = *(const float4*)(qbase + (size_t)li * D3 + kb + u * 4);
        float4 kv = *(const float4*)(kbase + (size_t)li * D3 + kb + u * 4);
        Qs[kb + u * 4 + 0][li] = qv.x; Qs[kb + u * 4 + 1][li] = qv.y;
        Qs[kb + u * 4 + 2][li] = qv.z; Qs[kb + u * 4 + 3][li] = qv.w;
        Ks[kb + u * 4 + 0][li] = kv.x; Ks[kb + u * 4 + 1][li] = kv.y;
        Ks[kb + u * 4 + 2][li] = kv.z; Ks[kb + u * 4 + 3][li] = kv.w;
    }
    __syncthreads();
    int tx = tid & 15, ty = tid >> 4;
    float acc[4][4] = {};
#pragma unroll
    for (int kk = 0; kk < 64; kk++) {
        float4 a = *(float4*)&Qs[kk][ty * 4];
        float4 b = *(float4*)&Ks[kk][tx * 4];
        float ar[4] = {a.x, a.y, a.z, a.w};
        float br[4] = {b.x, b.y, b.z, b.w};
#pragma unroll
        for (int r = 0; r < 4; r++)
#pragma unroll
            for (int c = 0; c < 4; c++)
                acc[r][c] += ar[r] * br[c];
    }
    float* sbase = S + (size_t)bh * NN;
#pragma unroll
    for (int r = 0; r < 4; r++) {
        int i = i0 + ty * 4 + r;
        float4 o;
        o.x = acc[r][0] * 0.125f; o.y = acc[r][1] * 0.125f;
        o.z = acc[r][2] * 0.125f; o.w = acc[r][3] * 0.125f;
        *(float4*)(sbase + (size_t)i * SEQ + j0 + tx * 4) = o;
    }
}

// monotonic float->uint map (ascending float order == ascending uint order)
__device__ __forceinline__ unsigned mono(float x) {
    unsigned b = __float_as_uint(x);
    return b ^ (((int)b >> 31) | 0x80000000u);
}

// ---------------- radix-select histogram pass ----------------
// grid (256, 48); each block: 256 thr x 4 float4 = 4096 elements
__global__ __launch_bounds__(256) void k_hist(const float* __restrict__ S,
                                              const unsigned* __restrict__ prefix,
                                              unsigned* __restrict__ hist,
                                              int shift, unsigned maskhi) {
    __shared__ unsigned lh[256];
    int tid = threadIdx.x;
    lh[tid] = 0u;
    __syncthreads();
    int bh = blockIdx.y;
    unsigned pfx = prefix[bh];
    const float4* p = (const float4*)(S + (size_t)bh * NN);
#pragma unroll
    for (int it = 0; it < 4; it++) {
        float4 v = p[(size_t)blockIdx.x * 1024 + it * 256 + tid];
        unsigned u[4] = {mono(v.x), mono(v.y), mono(v.z), mono(v.w)};
#pragma unroll
        for (int e = 0; e < 4; e++)
            if ((u[e] & maskhi) == pfx)
                atomicAdd(&lh[(u[e] >> shift) & 255u], 1u);
    }
    __syncthreads();
    unsigned c = lh[tid];
    if (c) atomicAdd(&hist[bh * 256 + tid], c);
}

// ---------------- radix-select scan (1 block, 48 active threads) ----------------
__global__ void k_select(unsigned* __restrict__ hist, unsigned* __restrict__ prefix,
                         unsigned* __restrict__ krem, float* __restrict__ thr,
                         int shift, int last) {
    int bh = threadIdx.x;
    if (bh >= BH) return;
    unsigned* hrow = hist + bh * 256;
    unsigned k = krem[bh];
    unsigned run = 0;
    int digit = 255;
    for (int d = 0; d < 256; d++) {
        unsigned c = hrow[d];
        if (run + c >= k) { digit = d; break; }
        run += c;
    }
    for (int d = 0; d < 256; d++) hrow[d] = 0u;   // reset for next pass
    prefix[bh] |= (unsigned)digit << shift;
    krem[bh] = k - run;
    if (last) {
        unsigned u = prefix[bh];
        unsigned bits = (u & 0x80000000u) ? (u ^ 0x80000000u) : ~u;
        thr[bh] = __uint_as_float(bits);
    }
}

// ---------------- per-row softmax stats (m, l) with masking ----------------
// one block per row (BH*SEQ blocks), 256 threads, 4 elems each
__global__ __launch_bounds__(256) void k_rowstats(const float* __restrict__ S,
                                                  const float* __restrict__ thr,
                                                  float* __restrict__ rowm,
                                                  float* __restrict__ rowl) {
    int row = blockIdx.x;
    int bh = row >> 10;
    float t = thr[bh];
    int tid = threadIdx.x;
    float4 v = *((const float4*)(S + (size_t)row * SEQ) + tid);
    float x[4] = {v.x, v.y, v.z, v.w};
#pragma unroll
    for (int u = 0; u < 4; u++) x[u] = (x[u] <= t) ? -1e9f : x[u];
    float m = fmaxf(fmaxf(x[0], x[1]), fmaxf(x[2], x[3]));
#pragma unroll
    for (int off = 1; off < 64; off <<= 1) m = fmaxf(m, __shfl_xor(m, off));
    __shared__ float wm[4], wl[4];
    int wave = tid >> 6, lane = tid & 63;
    if (lane == 0) wm[wave] = m;
    __syncthreads();
    m = fmaxf(fmaxf(wm[0], wm[1]), fmaxf(wm[2], wm[3]));
    float s = 0.f;
#pragma unroll
    for (int u = 0; u < 4; u++) s += expf(x[u] - m);
#pragma unroll
    for (int off = 1; off < 64; off <<= 1) s += __shfl_xor(s, off);
    if (lane == 0) wl[wave] = s;
    __syncthreads();
    if (tid == 0) {
        rowm[row] = m;
        rowl[row] = wl[0] + wl[1] + wl[2] + wl[3];
    }
}

// ---------------- PV: ctx[b,i,h*64+d] = sum_j softmax(S)_ij * V_jd ----------------
// grid (16, 48): 64 rows per block; BK=16 over j; 256 thr, 4x4 micro
__global__ __launch_bounds__(256) void k_pv(const float* __restrict__ S,
                                            const float* __restrict__ qkv,
                                            const float* __restrict__ thr,
                                            const float* __restrict__ rowm,
                                            const float* __restrict__ rowl,
                                            float* __restrict__ ctx) {
    int bh = blockIdx.y;
    int b = bh / NHEADS, h = bh % NHEADS;
    int i0 = blockIdx.x * 64;
    __shared__ float Ps[16][64];   // [jj][i]
    __shared__ float Vs[16][64];   // [jj][d]
    __shared__ float ml[64];
    int tid = threadIdx.x;
    if (tid < 64) ml[tid] = rowm[bh * SEQ + i0 + tid];
    float t = thr[bh];
    int tx = tid & 15, ty = tid >> 4;
    int pi = tid >> 2;             // 0..63 (row)
    int pj = (tid & 3) * 4;        // 0,4,8,12
    int vk = tid >> 4;             // 0..15 (j within tile)
    int vd = (tid & 15) * 4;       // 0..60
    const float* sbase = S + (size_t)bh * NN + (size_t)(i0 + pi) * SEQ;
    const float* vbase = qkv + (size_t)b * SEQ * D3 + 2 * DMODEL + h * HDIM;
    float acc[4][4] = {};
    __syncthreads();               // ml ready
    float mrow = ml[pi];
    for (int j0 = 0; j0 < SEQ; j0 += 16) {
        float4 sv = *(const float4*)(sbase + j0 + pj);
        float4 vv = *(const float4*)(vbase + (size_t)(j0 + vk) * D3 + vd);
        __syncthreads();
        Ps[pj + 0][pi] = expf(((sv.x <= t) ? -1e9f : sv.x) - mrow);
        Ps[pj + 1][pi] = expf(((sv.y <= t) ? -1e9f : sv.y) - mrow);
        Ps[pj + 2][pi] = expf(((sv.z <= t) ? -1e9f : sv.z) - mrow);
        Ps[pj + 3][pi] = expf(((sv.w <= t) ? -1e9f : sv.w) - mrow);
        *(float4*)&Vs[vk][vd] = vv;
        __syncthreads();
#pragma unroll
        for (int kk = 0; kk < 16; kk++) {
            float4 a = *(float4*)&Ps[kk][ty * 4];
            float4 bv = *(float4*)&Vs[kk][tx * 4];
            float ar[4] = {a.x, a.y, a.z, a.w};
            float br[4] = {bv.x, bv.y, bv.z, bv.w};
#pragma unroll
            for (int r = 0; r < 4; r++)
#pragma unroll
                for (int c = 0; c < 4; c++)
                    acc[r][c] += ar[r] * br[c];
        }
    }
#pragma unroll
    for (int r = 0; r < 4; r++) {
        int i = i0 + ty * 4 + r;
        float inv = 1.0f / rowl[bh * SEQ + i];
        float4 o;
        o.x = acc[r][0] * inv; o.y = acc[r][1] * inv;
        o.z = acc[r][2] * inv; o.w = acc[r][3] * inv;
        *(float4*)(ctx + (size_t)(b * SEQ + i) * DMODEL + h * HDIM + tx * 4) = o;
    }
}

extern "C" void kernel_launch(void* const* d_in, const int* in_sizes, int n_in,
                              void* d_out, int out_size, void* d_ws, size_t ws_size,
                              hipStream_t stream) {
    const float* x    = (const float*)d_in[0];
    const float* Wqkv = (const float*)d_in[1];
    const float* bqkv = (const float*)d_in[2];
    const float* Wout = (const float*)d_in[3];
    const float* bout = (const float*)d_in[4];
    float* out = (float*)d_out;

    char* ws = (char*)d_ws;
    float*    qkv    = (float*)ws;                          // 37,748,736 B
    float*    S      = (float*)(ws + 37748736);             // 201,326,592 B
    float*    ctx    = (float*)(ws + 239075328);            // 12,582,912 B
    unsigned* hist   = (unsigned*)(ws + 251658240);         // 49,152 B
    unsigned* prefix = (unsigned*)(ws + 251707392);         // 192 B
    unsigned* krem   = (unsigned*)(ws + 251707584);         // 192 B
    float*    thr    = (float*)(ws + 251707776);            // 192 B
    float*    rowm   = (float*)(ws + 251707968);            // 196,608 B
    float*    rowl   = (float*)(ws + 251904576);            // 196,608 B

    k_init<<<48, 256, 0, stream>>>(hist, prefix, krem);
    // qkv = x @ W_qkv + b_qkv
    k_gemm_bias<<<dim3(36, 64), 256, 0, stream>>>(x, Wqkv, bqkv, qkv, NTOK, D3, DMODEL);
    // S = Q K^T / 8
    k_scores<<<dim3(16, 16, BH), 256, 0, stream>>>(qkv, S);
    // exact kth-smallest per (b,h): 4-pass radix select on monotonic bits
    for (int p = 0; p < 4; p++) {
        int shift = 24 - 8 * p;
        unsigned maskhi = p ? (0xFFFFFFFFu << (32 - 8 * p)) : 0u;
        k_hist<<<dim3(256, BH), 256, 0, stream>>>(S, prefix, hist, shift, maskhi);
        k_select<<<1, 64, 0, stream>>>(hist, prefix, krem, thr, shift, (p == 3) ? 1 : 0);
    }
    // masked softmax row stats
    k_rowstats<<<BH * SEQ, 256, 0, stream>>>(S, thr, rowm, rowl);
    // ctx = softmax(masked S) @ V
    k_pv<<<dim3(16, BH), 256, 0, stream>>>(S, qkv, thr, rowm, rowl, ctx);
    // out = ctx @ W_out + b_out
    k_gemm_bias<<<dim3(12, 64), 256, 0, stream>>>(ctx, Wout, bout, out, NTOK, DMODEL, DMODEL);
}

// Round 2
// 671.176 us; speedup vs baseline: 1.2337x; 1.2337x over previous
//
#include <hip/hip_runtime.h>
#include <math.h>

#define BATCH 4
#define SEQ 1024
#define DMODEL 768
#define NHEADS 12
#define HDIM 64
#define D3 2304
#define BH 48            // BATCH*NHEADS
#define NTOK 4096        // BATCH*SEQ
#define NN (SEQ*SEQ)     // 1048576
#define KTH 104857u      // int(1024*1024*0.1)

typedef __bf16 bf16x8 __attribute__((ext_vector_type(8)));
typedef float  f32x4  __attribute__((ext_vector_type(4)));

// ---------------- fp32 -> (bf16 hi, bf16 lo) split, RNE ----------------
__device__ __forceinline__ void split1(float x, ushort& h, ushort& l) {
    unsigned b  = __float_as_uint(x);
    unsigned hb = (b + 0x7FFFu + ((b >> 16) & 1u)) >> 16;   // RNE to bf16
    float hf = __uint_as_float(hb << 16);
    float r  = x - hf;
    unsigned rb = __float_as_uint(r);
    unsigned lb = (rb + 0x7FFFu + ((rb >> 16) & 1u)) >> 16;
    h = (ushort)hb; l = (ushort)lb;
}

// ---------------- init: zero histograms, reset select state ----------------
__global__ void k_init(unsigned* __restrict__ hist, unsigned* __restrict__ prefix,
                       unsigned* __restrict__ krem) {
    int t = blockIdx.x * 256 + threadIdx.x;
    if (t < BH * 256) hist[t] = 0u;
    if (t < BH) { prefix[t] = 0u; krem[t] = KTH; }
}

// ---------------- elementwise split: x -> xh, xl ----------------
__global__ __launch_bounds__(256) void k_xsplit(const float* __restrict__ x,
                                                ushort* __restrict__ xh,
                                                ushort* __restrict__ xl, int n) {
    int i = (blockIdx.x * 256 + threadIdx.x) * 4;
    if (i >= n) return;
    float4 v = *(const float4*)(x + i);
    ushort4 h, l;
    split1(v.x, h.x, l.x); split1(v.y, h.y, l.y);
    split1(v.z, h.z, l.z); split1(v.w, h.w, l.w);
    *(ushort4*)(xh + i) = h;
    *(ushort4*)(xl + i) = l;
}

// ---------------- transpose + split: W[K][N] -> Wt_h/Wt_l [N][K] ----------------
// grid (N/64, K/64), 256 threads
__global__ __launch_bounds__(256) void k_wsplit(const float* __restrict__ W,
                                                ushort* __restrict__ Wth,
                                                ushort* __restrict__ Wtl,
                                                int K, int N) {
    __shared__ float t[64][65];
    int k0 = blockIdx.y * 64, n0 = blockIdx.x * 64;
    int tid = threadIdx.x;
    int r = tid >> 4, c = (tid & 15) * 4;
#pragma unroll
    for (int u = 0; u < 4; u++) {
        int rr = r + u * 16;
        float4 v = *(const float4*)(W + (size_t)(k0 + rr) * N + n0 + c);
        t[rr][c] = v.x; t[rr][c + 1] = v.y; t[rr][c + 2] = v.z; t[rr][c + 3] = v.w;
    }
    __syncthreads();
    int n = tid >> 2, kc = (tid & 3) * 16;
    ushort hb[16] __attribute__((aligned(16)));
    ushort lb[16] __attribute__((aligned(16)));
#pragma unroll
    for (int j = 0; j < 16; j++) split1(t[kc + j][n], hb[j], lb[j]);
    ushort* dh = Wth + (size_t)(n0 + n) * K + k0 + kc;
    ushort* dl = Wtl + (size_t)(n0 + n) * K + k0 + kc;
    *(uint4*)(dh)     = *(uint4*)&hb[0];
    *(uint4*)(dh + 8) = *(uint4*)&hb[8];
    *(uint4*)(dl)     = *(uint4*)&lb[0];
    *(uint4*)(dl + 8) = *(uint4*)&lb[8];
}

// ---------------- bf16x3 MFMA GEMM: C = A@B + bias ----------------
// A split: Ah/Al [M][K] bf16; B split+transposed: Bh/Bl [N][K] bf16.
// 128x128 tile, BK=32, 4 waves (2x2), each wave 64x64 via 4x4 of 16x16x32 MFMA.
#define LDK 40   // LDS row stride in bf16 elems (80 B = 20 dwords -> <=2-way conflicts)
__global__ __launch_bounds__(256) void k_gemm_mfma(
    const ushort* __restrict__ Ah, const ushort* __restrict__ Al,
    const ushort* __restrict__ Bh, const ushort* __restrict__ Bl,
    const float* __restrict__ bias, float* __restrict__ C,
    int M, int N, int K) {
    __shared__ ushort sAh[128 * LDK], sAl[128 * LDK];
    __shared__ ushort sBh[128 * LDK], sBl[128 * LDK];
    int tid = threadIdx.x;
    int lane = tid & 63;
    int wave = tid >> 6;
    int wm = (wave >> 1) * 64, wn = (wave & 1) * 64;
    int m0 = blockIdx.y * 128, n0 = blockIdx.x * 128;
    int l15 = lane & 15, q = lane >> 4;

    int srow = tid >> 2;            // 0..63
    int schunk = (tid & 3) * 8;     // 0,8,16,24 (bf16 elems)
    const ushort* gAh = Ah + (size_t)(m0 + srow) * K + schunk;
    const ushort* gAl = Al + (size_t)(m0 + srow) * K + schunk;
    const ushort* gBh = Bh + (size_t)(n0 + srow) * K + schunk;
    const ushort* gBl = Bl + (size_t)(n0 + srow) * K + schunk;
    size_t rstep = (size_t)64 * K;  // +64 rows

    int woffA = srow * LDK + schunk;
    int woffA2 = (srow + 64) * LDK + schunk;

    f32x4 acc[4][4] = {};           // [mt][nt]

    for (int k0 = 0; k0 < K; k0 += 32) {
        uint4 a0 = *(const uint4*)(gAh + k0);
        uint4 a1 = *(const uint4*)(gAh + rstep + k0);
        uint4 a2 = *(const uint4*)(gAl + k0);
        uint4 a3 = *(const uint4*)(gAl + rstep + k0);
        uint4 b0 = *(const uint4*)(gBh + k0);
        uint4 b1 = *(const uint4*)(gBh + rstep + k0);
        uint4 b2 = *(const uint4*)(gBl + k0);
        uint4 b3 = *(const uint4*)(gBl + rstep + k0);
        __syncthreads();
        *(uint4*)(sAh + woffA)  = a0;
        *(uint4*)(sAh + woffA2) = a1;
        *(uint4*)(sAl + woffA)  = a2;
        *(uint4*)(sAl + woffA2) = a3;
        *(uint4*)(sBh + woffA)  = b0;
        *(uint4*)(sBh + woffA2) = b1;
        *(uint4*)(sBl + woffA)  = b2;
        *(uint4*)(sBl + woffA2) = b3;
        __syncthreads();
        bf16x8 fah[4], fal[4], fbh[4], fbl[4];
#pragma unroll
        for (int mt = 0; mt < 4; mt++) {
            int off = (wm + mt * 16 + l15) * LDK + q * 8;
            fah[mt] = *(const bf16x8*)(sAh + off);
            fal[mt] = *(const bf16x8*)(sAl + off);
        }
#pragma unroll
        for (int nt = 0; nt < 4; nt++) {
            int off = (wn + nt * 16 + l15) * LDK + q * 8;
            fbh[nt] = *(const bf16x8*)(sBh + off);
            fbl[nt] = *(const bf16x8*)(sBl + off);
        }
#pragma unroll
        for (int mt = 0; mt < 4; mt++)
#pragma unroll
            for (int nt = 0; nt < 4; nt++) {
                acc[mt][nt] = __builtin_amdgcn_mfma_f32_16x16x32_bf16(
                    fah[mt], fbh[nt], acc[mt][nt], 0, 0, 0);
                acc[mt][nt] = __builtin_amdgcn_mfma_f32_16x16x32_bf16(
                    fah[mt], fbl[nt], acc[mt][nt], 0, 0, 0);
                acc[mt][nt] = __builtin_amdgcn_mfma_f32_16x16x32_bf16(
                    fal[mt], fbh[nt], acc[mt][nt], 0, 0, 0);
            }
    }
    // epilogue: C/D layout col=lane&15, row=(lane>>4)*4+reg
#pragma unroll
    for (int nt = 0; nt < 4; nt++) {
        int col = n0 + wn + nt * 16 + l15;
        float bv = bias[col];
#pragma unroll
        for (int mt = 0; mt < 4; mt++) {
            int rowb = m0 + wm + mt * 16 + q * 4;
#pragma unroll
            for (int r = 0; r < 4; r++)
                C[(size_t)(rowb + r) * N + col] = acc[mt][nt][r] + bv;
        }
    }
}

// ---------------- scores: S[bh,i,j] = (q_i . k_j) / 8 ----------------
__global__ __launch_bounds__(256) void k_scores(const float* __restrict__ qkv,
                                                float* __restrict__ S) {
    int bh = blockIdx.z;
    int b = bh / NHEADS, h = bh % NHEADS;
    int i0 = blockIdx.y * 64, j0 = blockIdx.x * 64;
    __shared__ float Qs[64][64];   // [kk][i]
    __shared__ float Ks[64][64];   // [kk][j]
    int tid = threadIdx.x;
    int li = tid >> 2;             // 0..63
    int kb = (tid & 3) * 16;       // 0,16,32,48
    const float* qbase = qkv + (size_t)(b * SEQ + i0) * D3 + h * HDIM;
    const float* kbase = qkv + (size_t)(b * SEQ + j0) * D3 + DMODEL + h * HDIM;
#pragma unroll
    for (int u = 0; u < 4; u++) {
        float4 qv = *(const float4*)(qbase + (size_t)li * D3 + kb + u * 4);
        float4 kv = *(const float4*)(kbase + (size_t)li * D3 + kb + u * 4);
        Qs[kb + u * 4 + 0][li] = qv.x; Qs[kb + u * 4 + 1][li] = qv.y;
        Qs[kb + u * 4 + 2][li] = qv.z; Qs[kb + u * 4 + 3][li] = qv.w;
        Ks[kb + u * 4 + 0][li] = kv.x; Ks[kb + u * 4 + 1][li] = kv.y;
        Ks[kb + u * 4 + 2][li] = kv.z; Ks[kb + u * 4 + 3][li] = kv.w;
    }
    __syncthreads();
    int tx = tid & 15, ty = tid >> 4;
    float acc[4][4] = {};
#pragma unroll
    for (int kk = 0; kk < 64; kk++) {
        float4 a = *(float4*)&Qs[kk][ty * 4];
        float4 b = *(float4*)&Ks[kk][tx * 4];
        float ar[4] = {a.x, a.y, a.z, a.w};
        float br[4] = {b.x, b.y, b.z, b.w};
#pragma unroll
        for (int r = 0; r < 4; r++)
#pragma unroll
            for (int c = 0; c < 4; c++)
                acc[r][c] += ar[r] * br[c];
    }
    float* sbase = S + (size_t)bh * NN;
#pragma unroll
    for (int r = 0; r < 4; r++) {
        int i = i0 + ty * 4 + r;
        float4 o;
        o.x = acc[r][0] * 0.125f; o.y = acc[r][1] * 0.125f;
        o.z = acc[r][2] * 0.125f; o.w = acc[r][3] * 0.125f;
        *(float4*)(sbase + (size_t)i * SEQ + j0 + tx * 4) = o;
    }
}

// monotonic float->uint map (ascending float order == ascending uint order)
__device__ __forceinline__ unsigned mono(float x) {
    unsigned b = __float_as_uint(x);
    return b ^ (((int)b >> 31) | 0x80000000u);
}

// ---------------- radix-select histogram pass ----------------
__global__ __launch_bounds__(256) void k_hist(const float* __restrict__ S,
                                              const unsigned* __restrict__ prefix,
                                              unsigned* __restrict__ hist,
                                              int shift, unsigned maskhi) {
    __shared__ unsigned lh[256];
    int tid = threadIdx.x;
    lh[tid] = 0u;
    __syncthreads();
    int bh = blockIdx.y;
    unsigned pfx = prefix[bh];
    const float4* p = (const float4*)(S + (size_t)bh * NN);
#pragma unroll
    for (int it = 0; it < 4; it++) {
        float4 v = p[(size_t)blockIdx.x * 1024 + it * 256 + tid];
        unsigned u[4] = {mono(v.x), mono(v.y), mono(v.z), mono(v.w)};
#pragma unroll
        for (int e = 0; e < 4; e++)
            if ((u[e] & maskhi) == pfx)
                atomicAdd(&lh[(u[e] >> shift) & 255u], 1u);
    }
    __syncthreads();
    unsigned c = lh[tid];
    if (c) atomicAdd(&hist[bh * 256 + tid], c);
}

// ---------------- radix-select scan (1 block, 48 active threads) ----------------
__global__ void k_select(unsigned* __restrict__ hist, unsigned* __restrict__ prefix,
                         unsigned* __restrict__ krem, float* __restrict__ thr,
                         int shift, int last) {
    int bh = threadIdx.x;
    if (bh >= BH) return;
    unsigned* hrow = hist + bh * 256;
    unsigned k = krem[bh];
    unsigned run = 0;
    int digit = 255;
    for (int d = 0; d < 256; d++) {
        unsigned c = hrow[d];
        if (run + c >= k) { digit = d; break; }
        run += c;
    }
    for (int d = 0; d < 256; d++) hrow[d] = 0u;   // reset for next pass
    prefix[bh] |= (unsigned)digit << shift;
    krem[bh] = k - run;
    if (last) {
        unsigned u = prefix[bh];
        unsigned bits = (u & 0x80000000u) ? (u ^ 0x80000000u) : ~u;
        thr[bh] = __uint_as_float(bits);
    }
}

// ---------------- per-row softmax stats (m, l) with masking ----------------
__global__ __launch_bounds__(256) void k_rowstats(const float* __restrict__ S,
                                                  const float* __restrict__ thr,
                                                  float* __restrict__ rowm,
                                                  float* __restrict__ rowl) {
    int row = blockIdx.x;
    int bh = row >> 10;
    float t = thr[bh];
    int tid = threadIdx.x;
    float4 v = *((const float4*)(S + (size_t)row * SEQ) + tid);
    float x[4] = {v.x, v.y, v.z, v.w};
#pragma unroll
    for (int u = 0; u < 4; u++) x[u] = (x[u] <= t) ? -1e9f : x[u];
    float m = fmaxf(fmaxf(x[0], x[1]), fmaxf(x[2], x[3]));
#pragma unroll
    for (int off = 1; off < 64; off <<= 1) m = fmaxf(m, __shfl_xor(m, off));
    __shared__ float wm[4], wl[4];
    int wave = tid >> 6, lane = tid & 63;
    if (lane == 0) wm[wave] = m;
    __syncthreads();
    m = fmaxf(fmaxf(wm[0], wm[1]), fmaxf(wm[2], wm[3]));
    float s = 0.f;
#pragma unroll
    for (int u = 0; u < 4; u++) s += expf(x[u] - m);
#pragma unroll
    for (int off = 1; off < 64; off <<= 1) s += __shfl_xor(s, off);
    if (lane == 0) wl[wave] = s;
    __syncthreads();
    if (tid == 0) {
        rowm[row] = m;
        rowl[row] = wl[0] + wl[1] + wl[2] + wl[3];
    }
}

// ---------------- PV: ctx = softmax(masked S) @ V, output split to bf16 hi/lo ----
__global__ __launch_bounds__(256) void k_pv(const float* __restrict__ S,
                                            const float* __restrict__ qkv,
                                            const float* __restrict__ thr,
                                            const float* __restrict__ rowm,
                                            const float* __restrict__ rowl,
                                            ushort* __restrict__ ctxh,
                                            ushort* __restrict__ ctxl) {
    int bh = blockIdx.y;
    int b = bh / NHEADS, h = bh % NHEADS;
    int i0 = blockIdx.x * 64;
    __shared__ float Ps[16][64];   // [jj][i]
    __shared__ float Vs[16][64];   // [jj][d]
    __shared__ float ml[64];
    int tid = threadIdx.x;
    if (tid < 64) ml[tid] = rowm[bh * SEQ + i0 + tid];
    float t = thr[bh];
    int tx = tid & 15, ty = tid >> 4;
    int pi = tid >> 2;             // 0..63 (row)
    int pj = (tid & 3) * 4;        // 0,4,8,12
    int vk = tid >> 4;             // 0..15 (j within tile)
    int vd = (tid & 15) * 4;       // 0..60
    const float* sbase = S + (size_t)bh * NN + (size_t)(i0 + pi) * SEQ;
    const float* vbase = qkv + (size_t)b * SEQ * D3 + 2 * DMODEL + h * HDIM;
    float acc[4][4] = {};
    __syncthreads();               // ml ready
    float mrow = ml[pi];
    for (int j0 = 0; j0 < SEQ; j0 += 16) {
        float4 sv = *(const float4*)(sbase + j0 + pj);
        float4 vv = *(const float4*)(vbase + (size_t)(j0 + vk) * D3 + vd);
        __syncthreads();
        Ps[pj + 0][pi] = expf(((sv.x <= t) ? -1e9f : sv.x) - mrow);
        Ps[pj + 1][pi] = expf(((sv.y <= t) ? -1e9f : sv.y) - mrow);
        Ps[pj + 2][pi] = expf(((sv.z <= t) ? -1e9f : sv.z) - mrow);
        Ps[pj + 3][pi] = expf(((sv.w <= t) ? -1e9f : sv.w) - mrow);
        *(float4*)&Vs[vk][vd] = vv;
        __syncthreads();
#pragma unroll
        for (int kk = 0; kk < 16; kk++) {
            float4 a = *(float4*)&Ps[kk][ty * 4];
            float4 bv = *(float4*)&Vs[kk][tx * 4];
            float ar[4] = {a.x, a.y, a.z, a.w};
            float br[4] = {bv.x, bv.y, bv.z, bv.w};
#pragma unroll
            for (int r = 0; r < 4; r++)
#pragma unroll
                for (int c = 0; c < 4; c++)
                    acc[r][c] += ar[r] * br[c];
        }
    }
#pragma unroll
    for (int r = 0; r < 4; r++) {
        int i = i0 + ty * 4 + r;
        float inv = 1.0f / rowl[bh * SEQ + i];
        ushort4 oh, ol;
        split1(acc[r][0] * inv, oh.x, ol.x);
        split1(acc[r][1] * inv, oh.y, ol.y);
        split1(acc[r][2] * inv, oh.z, ol.z);
        split1(acc[r][3] * inv, oh.w, ol.w);
        size_t off = (size_t)(b * SEQ + i) * DMODEL + h * HDIM + tx * 4;
        *(ushort4*)(ctxh + off) = oh;
        *(ushort4*)(ctxl + off) = ol;
    }
}

extern "C" void kernel_launch(void* const* d_in, const int* in_sizes, int n_in,
                              void* d_out, int out_size, void* d_ws, size_t ws_size,
                              hipStream_t stream) {
    const float* x    = (const float*)d_in[0];
    const float* Wqkv = (const float*)d_in[1];
    const float* bqkv = (const float*)d_in[2];
    const float* Wout = (const float*)d_in[3];
    const float* bout = (const float*)d_in[4];
    float* out = (float*)d_out;

    char* ws = (char*)d_ws;
    float*    qkv    = (float*)ws;                          // 37,748,736 B
    float*    S      = (float*)(ws + 37748736);             // 201,326,592 B
    unsigned* hist   = (unsigned*)(ws + 251658240);         // 49,152 B
    unsigned* prefix = (unsigned*)(ws + 251707392);         // 192 B
    unsigned* krem   = (unsigned*)(ws + 251707584);         // 192 B
    float*    thr    = (float*)(ws + 251707776);            // 192 B
    float*    rowm   = (float*)(ws + 251707968);            // 196,608 B
    float*    rowl   = (float*)(ws + 251904576);            // 196,608 B

    // overlays inside the S region (dead before k_scores writes S):
    ushort* xh     = (ushort*)(ws + 37748736);                    // 6,291,456 B
    ushort* xl     = (ushort*)(ws + 37748736 + 6291456);          // 6,291,456 B
    ushort* Wqkvth = (ushort*)(ws + 37748736 + 12582912);         // 3,538,944 B
    ushort* Wqkvtl = (ushort*)(ws + 37748736 + 16121856);         // 3,538,944 B
    // overlay inside S region (dead after k_pv):
    ushort* Woutth = (ushort*)(ws + 37748736);                    // 1,179,648 B
    ushort* Wouttl = (ushort*)(ws + 37748736 + 1179648);          // 1,179,648 B
    // ctx slot reused as bf16 hi/lo:
    ushort* ctxh   = (ushort*)(ws + 239075328);                   // 6,291,456 B
    ushort* ctxl   = (ushort*)(ws + 239075328 + 6291456);         // 6,291,456 B

    k_init<<<48, 256, 0, stream>>>(hist, prefix, krem);
    // split inputs for bf16x3 MFMA
    k_xsplit<<<NTOK * DMODEL / 1024, 256, 0, stream>>>(x, xh, xl, NTOK * DMODEL);
    k_wsplit<<<dim3(D3 / 64, DMODEL / 64), 256, 0, stream>>>(Wqkv, Wqkvth, Wqkvtl, DMODEL, D3);
    // qkv = x @ W_qkv + b_qkv  (bf16x3 MFMA)
    k_gemm_mfma<<<dim3(D3 / 128, NTOK / 128), 256, 0, stream>>>(
        xh, xl, Wqkvth, Wqkvtl, bqkv, qkv, NTOK, D3, DMODEL);
    // S = Q K^T / 8
    k_scores<<<dim3(16, 16, BH), 256, 0, stream>>>(qkv, S);
    // exact kth-smallest per (b,h): 4-pass radix select on monotonic bits
    for (int p = 0; p < 4; p++) {
        int shift = 24 - 8 * p;
        unsigned maskhi = p ? (0xFFFFFFFFu << (32 - 8 * p)) : 0u;
        k_hist<<<dim3(256, BH), 256, 0, stream>>>(S, prefix, hist, shift, maskhi);
        k_select<<<1, 64, 0, stream>>>(hist, prefix, krem, thr, shift, (p == 3) ? 1 : 0);
    }
    // masked softmax row stats
    k_rowstats<<<BH * SEQ, 256, 0, stream>>>(S, thr, rowm, rowl);
    // ctx = softmax(masked S) @ V  (writes bf16 hi/lo split directly)
    k_pv<<<dim3(16, BH), 256, 0, stream>>>(S, qkv, thr, rowm, rowl, ctxh, ctxl);
    // split W_out (S region is dead now)
    k_wsplit<<<dim3(DMODEL / 64, DMODEL / 64), 256, 0, stream>>>(Wout, Woutth, Wouttl, DMODEL, DMODEL);
    // out = ctx @ W_out + b_out  (bf16x3 MFMA)
    k_gemm_mfma<<<dim3(DMODEL / 128, NTOK / 128), 256, 0, stream>>>(
        ctxh, ctxl, Woutth, Wouttl, bout, out, NTOK, DMODEL, DMODEL);
}

// Round 3
// 525.317 us; speedup vs baseline: 1.5762x; 1.2777x over previous
//
#include <hip/hip_runtime.h>
#include <math.h>

#define SEQ 1024
#define DMODEL 768
#define NHEADS 12
#define HDIM 64
#define D3 2304
#define BH 48            // BATCH*NHEADS
#define NTOK 4096        // BATCH*SEQ
#define NN (SEQ*SEQ)     // 1048576
#define KTH 104857u      // int(1024*1024*0.1)
#define CAP 131072       // candidate slots per (b,h)

typedef __bf16 bf16x8 __attribute__((ext_vector_type(8)));
typedef float  f32x4  __attribute__((ext_vector_type(4)));

// ---------------- fp32 -> (bf16 hi, bf16 lo) split, RNE ----------------
__device__ __forceinline__ void split1(float x, ushort& h, ushort& l) {
    unsigned b  = __float_as_uint(x);
    unsigned hb = (b + 0x7FFFu + ((b >> 16) & 1u)) >> 16;   // RNE to bf16
    float hf = __uint_as_float(hb << 16);
    float r  = x - hf;
    unsigned rb = __float_as_uint(r);
    unsigned lb = (rb + 0x7FFFu + ((rb >> 16) & 1u)) >> 16;
    h = (ushort)hb; l = (ushort)lb;
}

__device__ __forceinline__ ushort bf16rne(float x) {
    unsigned b = __float_as_uint(x);
    return (ushort)((b + 0x7FFFu + ((b >> 16) & 1u)) >> 16);
}

// monotonic float->uint map (ascending float order == ascending uint order)
__device__ __forceinline__ unsigned mono(float x) {
    unsigned b = __float_as_uint(x);
    return b ^ (((int)b >> 31) | 0x80000000u);
}

// ---------------- init: zero histograms + candidate counters ----------------
__global__ void k_init(unsigned* __restrict__ hist, unsigned* __restrict__ cnt) {
    int t = blockIdx.x * 256 + threadIdx.x;
    if (t < BH * 2048) hist[t] = 0u;
    if (t < BH) cnt[t] = 0u;
}

// ---------------- elementwise split: x -> xh, xl ----------------
__global__ __launch_bounds__(256) void k_xsplit(const float* __restrict__ x,
                                                ushort* __restrict__ xh,
                                                ushort* __restrict__ xl, int n) {
    int i = (blockIdx.x * 256 + threadIdx.x) * 4;
    if (i >= n) return;
    float4 v = *(const float4*)(x + i);
    ushort4 h, l;
    split1(v.x, h.x, l.x); split1(v.y, h.y, l.y);
    split1(v.z, h.z, l.z); split1(v.w, h.w, l.w);
    *(ushort4*)(xh + i) = h;
    *(ushort4*)(xl + i) = l;
}

// ---------------- transpose + split: W[K][N] -> Wt_h/Wt_l [N][K] ----------------
__global__ __launch_bounds__(256) void k_wsplit(const float* __restrict__ W,
                                                ushort* __restrict__ Wth,
                                                ushort* __restrict__ Wtl,
                                                int K, int N) {
    __shared__ float t[64][65];
    int k0 = blockIdx.y * 64, n0 = blockIdx.x * 64;
    int tid = threadIdx.x;
    int r = tid >> 4, c = (tid & 15) * 4;
#pragma unroll
    for (int u = 0; u < 4; u++) {
        int rr = r + u * 16;
        float4 v = *(const float4*)(W + (size_t)(k0 + rr) * N + n0 + c);
        t[rr][c] = v.x; t[rr][c + 1] = v.y; t[rr][c + 2] = v.z; t[rr][c + 3] = v.w;
    }
    __syncthreads();
    int n = tid >> 2, kc = (tid & 3) * 16;
    ushort hb[16] __attribute__((aligned(16)));
    ushort lb[16] __attribute__((aligned(16)));
#pragma unroll
    for (int j = 0; j < 16; j++) split1(t[kc + j][n], hb[j], lb[j]);
    ushort* dh = Wth + (size_t)(n0 + n) * K + k0 + kc;
    ushort* dl = Wtl + (size_t)(n0 + n) * K + k0 + kc;
    *(uint4*)(dh)     = *(uint4*)&hb[0];
    *(uint4*)(dh + 8) = *(uint4*)&hb[8];
    *(uint4*)(dl)     = *(uint4*)&lb[0];
    *(uint4*)(dl + 8) = *(uint4*)&lb[8];
}

// ---------------- bf16x3 MFMA GEMM: C = A@B + bias (fp32 out) ----------------
#define LDK 40
__global__ __launch_bounds__(256) void k_gemm_mfma(
    const ushort* __restrict__ Ah, const ushort* __restrict__ Al,
    const ushort* __restrict__ Bh, const ushort* __restrict__ Bl,
    const float* __restrict__ bias, float* __restrict__ C,
    int M, int N, int K) {
    __shared__ ushort sAh[128 * LDK], sAl[128 * LDK];
    __shared__ ushort sBh[128 * LDK], sBl[128 * LDK];
    int tid = threadIdx.x;
    int lane = tid & 63;
    int wave = tid >> 6;
    int wm = (wave >> 1) * 64, wn = (wave & 1) * 64;
    int m0 = blockIdx.y * 128, n0 = blockIdx.x * 128;
    int l15 = lane & 15, q = lane >> 4;

    int srow = tid >> 2;
    int schunk = (tid & 3) * 8;
    const ushort* gAh = Ah + (size_t)(m0 + srow) * K + schunk;
    const ushort* gAl = Al + (size_t)(m0 + srow) * K + schunk;
    const ushort* gBh = Bh + (size_t)(n0 + srow) * K + schunk;
    const ushort* gBl = Bl + (size_t)(n0 + srow) * K + schunk;
    size_t rstep = (size_t)64 * K;

    int woffA = srow * LDK + schunk;
    int woffA2 = (srow + 64) * LDK + schunk;

    f32x4 acc[4][4] = {};

    for (int k0 = 0; k0 < K; k0 += 32) {
        uint4 a0 = *(const uint4*)(gAh + k0);
        uint4 a1 = *(const uint4*)(gAh + rstep + k0);
        uint4 a2 = *(const uint4*)(gAl + k0);
        uint4 a3 = *(const uint4*)(gAl + rstep + k0);
        uint4 b0 = *(const uint4*)(gBh + k0);
        uint4 b1 = *(const uint4*)(gBh + rstep + k0);
        uint4 b2 = *(const uint4*)(gBl + k0);
        uint4 b3 = *(const uint4*)(gBl + rstep + k0);
        __syncthreads();
        *(uint4*)(sAh + woffA)  = a0;
        *(uint4*)(sAh + woffA2) = a1;
        *(uint4*)(sAl + woffA)  = a2;
        *(uint4*)(sAl + woffA2) = a3;
        *(uint4*)(sBh + woffA)  = b0;
        *(uint4*)(sBh + woffA2) = b1;
        *(uint4*)(sBl + woffA)  = b2;
        *(uint4*)(sBl + woffA2) = b3;
        __syncthreads();
        bf16x8 fah[4], fal[4], fbh[4], fbl[4];
#pragma unroll
        for (int mt = 0; mt < 4; mt++) {
            int off = (wm + mt * 16 + l15) * LDK + q * 8;
            fah[mt] = *(const bf16x8*)(sAh + off);
            fal[mt] = *(const bf16x8*)(sAl + off);
        }
#pragma unroll
        for (int nt = 0; nt < 4; nt++) {
            int off = (wn + nt * 16 + l15) * LDK + q * 8;
            fbh[nt] = *(const bf16x8*)(sBh + off);
            fbl[nt] = *(const bf16x8*)(sBl + off);
        }
#pragma unroll
        for (int mt = 0; mt < 4; mt++)
#pragma unroll
            for (int nt = 0; nt < 4; nt++) {
                acc[mt][nt] = __builtin_amdgcn_mfma_f32_16x16x32_bf16(
                    fah[mt], fbh[nt], acc[mt][nt], 0, 0, 0);
                acc[mt][nt] = __builtin_amdgcn_mfma_f32_16x16x32_bf16(
                    fah[mt], fbl[nt], acc[mt][nt], 0, 0, 0);
                acc[mt][nt] = __builtin_amdgcn_mfma_f32_16x16x32_bf16(
                    fal[mt], fbh[nt], acc[mt][nt], 0, 0, 0);
            }
    }
#pragma unroll
    for (int nt = 0; nt < 4; nt++) {
        int col = n0 + wn + nt * 16 + l15;
        float bv = bias[col];
#pragma unroll
        for (int mt = 0; mt < 4; mt++) {
            int rowb = m0 + wm + mt * 16 + q * 4;
#pragma unroll
            for (int r = 0; r < 4; r++)
                C[(size_t)(rowb + r) * N + col] = acc[mt][nt][r] + bv;
        }
    }
}

// ---------------- QKV GEMM: same core, epilogue writes split Q/K straight +
// V transposed.  Qh/Ql/Kh/Kl: [bh][s][64] bf16.  Vth/Vtl: [bh][64][s] bf16.
__global__ __launch_bounds__(256) void k_gemm_qkv(
    const ushort* __restrict__ Ah, const ushort* __restrict__ Al,
    const ushort* __restrict__ Bh, const ushort* __restrict__ Bl,
    const float* __restrict__ bias,
    ushort* __restrict__ Qh, ushort* __restrict__ Ql,
    ushort* __restrict__ Kh, ushort* __restrict__ Kl,
    ushort* __restrict__ Vth, ushort* __restrict__ Vtl) {
    const int N = D3, K = DMODEL;
    __shared__ ushort sAh[128 * LDK], sAl[128 * LDK];
    __shared__ ushort sBh[128 * LDK], sBl[128 * LDK];
    int tid = threadIdx.x;
    int lane = tid & 63;
    int wave = tid >> 6;
    int wm = (wave >> 1) * 64, wn = (wave & 1) * 64;
    int m0 = blockIdx.y * 128, n0 = blockIdx.x * 128;
    int l15 = lane & 15, q = lane >> 4;

    int srow = tid >> 2;
    int schunk = (tid & 3) * 8;
    const ushort* gAh = Ah + (size_t)(m0 + srow) * K + schunk;
    const ushort* gAl = Al + (size_t)(m0 + srow) * K + schunk;
    const ushort* gBh = Bh + (size_t)(n0 + srow) * K + schunk;
    const ushort* gBl = Bl + (size_t)(n0 + srow) * K + schunk;
    size_t rstep = (size_t)64 * K;
    int woffA = srow * LDK + schunk;
    int woffA2 = (srow + 64) * LDK + schunk;

    f32x4 acc[4][4] = {};
    for (int k0 = 0; k0 < K; k0 += 32) {
        uint4 a0 = *(const uint4*)(gAh + k0);
        uint4 a1 = *(const uint4*)(gAh + rstep + k0);
        uint4 a2 = *(const uint4*)(gAl + k0);
        uint4 a3 = *(const uint4*)(gAl + rstep + k0);
        uint4 b0 = *(const uint4*)(gBh + k0);
        uint4 b1 = *(const uint4*)(gBh + rstep + k0);
        uint4 b2 = *(const uint4*)(gBl + k0);
        uint4 b3 = *(const uint4*)(gBl + rstep + k0);
        __syncthreads();
        *(uint4*)(sAh + woffA)  = a0;
        *(uint4*)(sAh + woffA2) = a1;
        *(uint4*)(sAl + woffA)  = a2;
        *(uint4*)(sAl + woffA2) = a3;
        *(uint4*)(sBh + woffA)  = b0;
        *(uint4*)(sBh + woffA2) = b1;
        *(uint4*)(sBl + woffA)  = b2;
        *(uint4*)(sBl + woffA2) = b3;
        __syncthreads();
        bf16x8 fah[4], fal[4], fbh[4], fbl[4];
#pragma unroll
        for (int mt = 0; mt < 4; mt++) {
            int off = (wm + mt * 16 + l15) * LDK + q * 8;
            fah[mt] = *(const bf16x8*)(sAh + off);
            fal[mt] = *(const bf16x8*)(sAl + off);
        }
#pragma unroll
        for (int nt = 0; nt < 4; nt++) {
            int off = (wn + nt * 16 + l15) * LDK + q * 8;
            fbh[nt] = *(const bf16x8*)(sBh + off);
            fbl[nt] = *(const bf16x8*)(sBl + off);
        }
#pragma unroll
        for (int mt = 0; mt < 4; mt++)
#pragma unroll
            for (int nt = 0; nt < 4; nt++) {
                acc[mt][nt] = __builtin_amdgcn_mfma_f32_16x16x32_bf16(
                    fah[mt], fbh[nt], acc[mt][nt], 0, 0, 0);
                acc[mt][nt] = __builtin_amdgcn_mfma_f32_16x16x32_bf16(
                    fah[mt], fbl[nt], acc[mt][nt], 0, 0, 0);
                acc[mt][nt] = __builtin_amdgcn_mfma_f32_16x16x32_bf16(
                    fal[mt], fbh[nt], acc[mt][nt], 0, 0, 0);
            }
    }
    // epilogue: region uniform per block (768 = 6*128)
    int region = n0 / 768;    // 0=Q, 1=K, 2=V
    int b = m0 >> 10;
#pragma unroll
    for (int nt = 0; nt < 4; nt++) {
        int col = n0 + wn + nt * 16 + l15;
        float bv = bias[col];
        int cin = col - region * 768;
        int h = cin >> 6, d = cin & 63;
        int bh = b * NHEADS + h;
#pragma unroll
        for (int mt = 0; mt < 4; mt++) {
            int s0 = (m0 + wm + mt * 16 + q * 4) & 1023;
            if (region == 2) {
                ushort h4[4] __attribute__((aligned(8)));
                ushort l4[4] __attribute__((aligned(8)));
#pragma unroll
                for (int r = 0; r < 4; r++)
                    split1(acc[mt][nt][r] + bv, h4[r], l4[r]);
                size_t off = ((size_t)(bh * 64 + d) << 10) + s0;
                *(ushort4*)(Vth + off) = *(ushort4*)h4;
                *(ushort4*)(Vtl + off) = *(ushort4*)l4;
            } else {
                ushort* Ph = region ? Kh : Qh;
                ushort* Pl = region ? Kl : Ql;
                size_t off = ((size_t)((bh << 10) + s0)) * 64 + d;
#pragma unroll
                for (int r = 0; r < 4; r++) {
                    ushort hs, ls;
                    split1(acc[mt][nt][r] + bv, hs, ls);
                    Ph[off + (size_t)r * 64] = hs;
                    Pl[off + (size_t)r * 64] = ls;
                }
            }
        }
    }
}

// ---------------- scores MFMA: S = Q K^T / 8, fused 11-bit histogram ----------
// grid (8, 8, 48), 128x128 tile, K=64 staged once.
__global__ __launch_bounds__(256) void k_scores_mfma(
    const ushort* __restrict__ Qh, const ushort* __restrict__ Ql,
    const ushort* __restrict__ Kh, const ushort* __restrict__ Kl,
    float* __restrict__ S, unsigned* __restrict__ hist) {
    __shared__ char smem[4 * 128 * 72 * 2];   // 73728 B
    ushort* sQh = (ushort*)smem;
    ushort* sQl = sQh + 128 * 72;
    ushort* sKh = sQl + 128 * 72;
    ushort* sKl = sKh + 128 * 72;
    int bh = blockIdx.z;
    int i0 = blockIdx.y * 128, j0 = blockIdx.x * 128;
    int tid = threadIdx.x, lane = tid & 63, wave = tid >> 6;
    int l15 = lane & 15, q = lane >> 4;
    int wm = (wave >> 1) * 64, wn = (wave & 1) * 64;

    int r = tid >> 2, c = (tid & 3) * 16;
    const ushort* gq = Qh + (((size_t)bh << 10) + i0 + r) * 64 + c;
    const ushort* gql = Ql + (((size_t)bh << 10) + i0 + r) * 64 + c;
    const ushort* gk = Kh + (((size_t)bh << 10) + j0 + r) * 64 + c;
    const ushort* gkl = Kl + (((size_t)bh << 10) + j0 + r) * 64 + c;
#pragma unroll
    for (int u = 0; u < 2; u++) {      // rows r and r+64
        size_t go = (size_t)u * 64 * 64;
        int lo = (r + u * 64) * 72 + c;
        *(uint4*)(sQh + lo)     = *(const uint4*)(gq + go);
        *(uint4*)(sQh + lo + 8) = *(const uint4*)(gq + go + 8);
        *(uint4*)(sQl + lo)     = *(const uint4*)(gql + go);
        *(uint4*)(sQl + lo + 8) = *(const uint4*)(gql + go + 8);
        *(uint4*)(sKh + lo)     = *(const uint4*)(gk + go);
        *(uint4*)(sKh + lo + 8) = *(const uint4*)(gk + go + 8);
        *(uint4*)(sKl + lo)     = *(const uint4*)(gkl + go);
        *(uint4*)(sKl + lo + 8) = *(const uint4*)(gkl + go + 8);
    }
    __syncthreads();
    f32x4 acc[4][4] = {};
#pragma unroll
    for (int kk = 0; kk < 64; kk += 32) {
        bf16x8 fqh[4], fql[4], fkh[4], fkl[4];
#pragma unroll
        for (int mt = 0; mt < 4; mt++) {
            int off = (wm + mt * 16 + l15) * 72 + kk + q * 8;
            fqh[mt] = *(const bf16x8*)(sQh + off);
            fql[mt] = *(const bf16x8*)(sQl + off);
        }
#pragma unroll
        for (int nt = 0; nt < 4; nt++) {
            int off = (wn + nt * 16 + l15) * 72 + kk + q * 8;
            fkh[nt] = *(const bf16x8*)(sKh + off);
            fkl[nt] = *(const bf16x8*)(sKl + off);
        }
#pragma unroll
        for (int mt = 0; mt < 4; mt++)
#pragma unroll
            for (int nt = 0; nt < 4; nt++) {
                acc[mt][nt] = __builtin_amdgcn_mfma_f32_16x16x32_bf16(
                    fqh[mt], fkh[nt], acc[mt][nt], 0, 0, 0);
                acc[mt][nt] = __builtin_amdgcn_mfma_f32_16x16x32_bf16(
                    fqh[mt], fkl[nt], acc[mt][nt], 0, 0, 0);
                acc[mt][nt] = __builtin_amdgcn_mfma_f32_16x16x32_bf16(
                    fql[mt], fkh[nt], acc[mt][nt], 0, 0, 0);
            }
    }
    __syncthreads();                   // LDS reuse: hist
    unsigned* lh = (unsigned*)smem;
    for (int i = tid; i < 2048; i += 256) lh[i] = 0u;
    __syncthreads();
    float* sb = S + (size_t)bh * NN;
#pragma unroll
    for (int mt = 0; mt < 4; mt++)
#pragma unroll
        for (int nt = 0; nt < 4; nt++) {
            int jj = j0 + wn + nt * 16 + l15;
            int ib = i0 + wm + mt * 16 + q * 4;
#pragma unroll
            for (int r2 = 0; r2 < 4; r2++) {
                float v = acc[mt][nt][r2] * 0.125f;
                sb[(size_t)(ib + r2) * SEQ + jj] = v;
                atomicAdd(&lh[mono(v) >> 21], 1u);
            }
        }
    __syncthreads();
    for (int i = tid; i < 2048; i += 256) {
        unsigned cc = lh[i];
        if (cc) atomicAdd(&hist[bh * 2048 + i], cc);
    }
}

// ---------------- select0: 2048-bin scan, one block per bh ----------------
__global__ void k_select0(unsigned* __restrict__ hist, unsigned* __restrict__ prefix,
                          unsigned* __restrict__ krem) {
    int bh = blockIdx.x;
    unsigned* hrow = hist + bh * 2048;
    __shared__ unsigned ps[256];
    __shared__ unsigned sdig, sbelow;
    int tid = threadIdx.x;
    unsigned s = 0;
#pragma unroll
    for (int i = 0; i < 8; i++) s += hrow[tid * 8 + i];
    ps[tid] = s;
    __syncthreads();
    if (tid == 0) {
        unsigned k = KTH, run = 0; int chunk = 255;
        for (int t2 = 0; t2 < 256; t2++) {
            if (run + ps[t2] >= k) { chunk = t2; break; }
            run += ps[t2];
        }
        int d = 7;
        for (int i = 0; i < 8; i++) {
            unsigned v = hrow[chunk * 8 + i];
            if (run + v >= k) { d = i; break; }
            run += v;
        }
        sdig = (unsigned)(chunk * 8 + d); sbelow = run;
    }
    __syncthreads();
#pragma unroll
    for (int i = 0; i < 8; i++) hrow[tid * 8 + i] = 0u;
    if (tid == 0) { prefix[bh] = sdig << 21; krem[bh] = KTH - sbelow; }
}

// ---------------- compact: full S scan, match 11-bit prefix -> cand + 8-bit hist
__global__ __launch_bounds__(256) void k_compact(const float* __restrict__ S,
                                                 const unsigned* __restrict__ prefix,
                                                 unsigned* __restrict__ hist,
                                                 unsigned* __restrict__ cnt,
                                                 float* __restrict__ cand) {
    __shared__ float buf[4096];
    __shared__ unsigned lh[256];
    __shared__ unsigned lcnt, gbase;
    int tid = threadIdx.x;
    if (tid == 0) lcnt = 0u;
    lh[tid] = 0u;
    __syncthreads();
    int bh = blockIdx.y;
    unsigned pm = prefix[bh] >> 21;
    const float4* p = (const float4*)(S + (size_t)bh * NN);
#pragma unroll
    for (int it = 0; it < 4; it++) {
        float4 v = p[(size_t)blockIdx.x * 1024 + it * 256 + tid];
        float vv[4] = {v.x, v.y, v.z, v.w};
#pragma unroll
        for (int e = 0; e < 4; e++) {
            unsigned u = mono(vv[e]);
            if ((u >> 21) == pm) {
                unsigned ix = atomicAdd(&lcnt, 1u);
                buf[ix] = vv[e];
                atomicAdd(&lh[(u >> 13) & 255u], 1u);
            }
        }
    }
    __syncthreads();
    if (tid == 0) gbase = atomicAdd(&cnt[bh], lcnt);
    unsigned c = lh[tid];
    if (c) atomicAdd(&hist[bh * 2048 + tid], c);
    __syncthreads();
    float* dst = cand + (size_t)bh * CAP;
    for (unsigned i = tid; i < lcnt; i += 256) dst[gbase + i] = buf[i];
}

// ---------------- candidate histogram pass ----------------
__global__ __launch_bounds__(256) void k_candhist(const float* __restrict__ cand,
                                                  const unsigned* __restrict__ cnt,
                                                  const unsigned* __restrict__ prefix,
                                                  unsigned* __restrict__ hist,
                                                  int ms, int ds, unsigned dm) {
    __shared__ unsigned lh[256];
    int tid = threadIdx.x;
    lh[tid] = 0u;
    __syncthreads();
    int bh = blockIdx.y;
    unsigned n = cnt[bh], pm = prefix[bh] >> ms;
    const float* cb = cand + (size_t)bh * CAP;
    for (unsigned i = blockIdx.x * 256 + tid; i < n; i += gridDim.x * 256) {
        unsigned u = mono(cb[i]);
        if ((u >> ms) == pm) atomicAdd(&lh[(u >> ds) & dm], 1u);
    }
    __syncthreads();
    unsigned c = lh[tid];
    if (c) atomicAdd(&hist[bh * 2048 + tid], c);
}

// ---------------- serial digit select (nbins <= 256) ----------------
__global__ void k_select(unsigned* __restrict__ hist, unsigned* __restrict__ prefix,
                         unsigned* __restrict__ krem, float* __restrict__ thr,
                         int shift, int nbins, int last) {
    int bh = threadIdx.x;
    if (bh >= BH) return;
    unsigned* hrow = hist + bh * 2048;
    unsigned k = krem[bh];
    unsigned run = 0;
    int digit = nbins - 1;
    for (int d = 0; d < nbins; d++) {
        unsigned c = hrow[d];
        if (run + c >= k) { digit = d; break; }
        run += c;
    }
    for (int d = 0; d < nbins; d++) hrow[d] = 0u;
    prefix[bh] |= (unsigned)digit << shift;
    krem[bh] = k - run;
    if (last) {
        unsigned u = prefix[bh];
        unsigned bits = (u & 0x80000000u) ? (u ^ 0x80000000u) : ~u;
        thr[bh] = __uint_as_float(bits);
    }
}

// ---------------- PV MFMA: ctx = softmax(masked S) @ V, l via ones-column ------
// grid (16, 48): 64 rows per block; P bf16 on the fly, V pre-split transposed.
__global__ __launch_bounds__(256) void k_pv(const float* __restrict__ S,
                                            const ushort* __restrict__ Vth,
                                            const ushort* __restrict__ Vtl,
                                            const float* __restrict__ thr,
                                            ushort* __restrict__ ctxh,
                                            ushort* __restrict__ ctxl) {
    int bh = blockIdx.y;
    int b = bh / NHEADS, h = bh % NHEADS;
    int s0 = blockIdx.x * 64;
    __shared__ ushort sP[64 * 40], sVh[64 * 40], sVl[64 * 40];
    int tid = threadIdx.x, lane = tid & 63, wave = tid >> 6;
    int l15 = lane & 15, q = lane >> 4;
    float t = thr[bh];
    int prow = tid >> 2, pk = (tid & 3) * 8;
    const float* srp = S + (size_t)bh * NN + (size_t)(s0 + prow) * SEQ + pk;
    const ushort* vhp = Vth + ((size_t)bh * 64 + prow) * 1024 + pk;
    const ushort* vlp = Vtl + ((size_t)bh * 64 + prow) * 1024 + pk;
    f32x4 acc[4] = {};
    f32x4 lacc = {};
    bf16x8 ones;
#pragma unroll
    for (int i = 0; i < 8; i++) ones[i] = (__bf16)1.0f;
    for (int j0 = 0; j0 < SEQ; j0 += 32) {
        float4 a = *(const float4*)(srp + j0);
        float4 bq = *(const float4*)(srp + j0 + 4);
        uint4 vh = *(const uint4*)(vhp + j0);
        uint4 vl = *(const uint4*)(vlp + j0);
        __syncthreads();
        ushort pb[8] __attribute__((aligned(16)));
        pb[0] = bf16rne((a.x  <= t) ? 0.f : __expf(a.x));
        pb[1] = bf16rne((a.y  <= t) ? 0.f : __expf(a.y));
        pb[2] = bf16rne((a.z  <= t) ? 0.f : __expf(a.z));
        pb[3] = bf16rne((a.w  <= t) ? 0.f : __expf(a.w));
        pb[4] = bf16rne((bq.x <= t) ? 0.f : __expf(bq.x));
        pb[5] = bf16rne((bq.y <= t) ? 0.f : __expf(bq.y));
        pb[6] = bf16rne((bq.z <= t) ? 0.f : __expf(bq.z));
        pb[7] = bf16rne((bq.w <= t) ? 0.f : __expf(bq.w));
        *(uint4*)(sP + prow * 40 + pk) = *(uint4*)pb;
        *(uint4*)(sVh + prow * 40 + pk) = vh;
        *(uint4*)(sVl + prow * 40 + pk) = vl;
        __syncthreads();
        bf16x8 fp = *(const bf16x8*)(sP + (wave * 16 + l15) * 40 + q * 8);
#pragma unroll
        for (int nt = 0; nt < 4; nt++) {
            int off = (nt * 16 + l15) * 40 + q * 8;
            bf16x8 fvh = *(const bf16x8*)(sVh + off);
            bf16x8 fvl = *(const bf16x8*)(sVl + off);
            acc[nt] = __builtin_amdgcn_mfma_f32_16x16x32_bf16(fp, fvh, acc[nt], 0, 0, 0);
            acc[nt] = __builtin_amdgcn_mfma_f32_16x16x32_bf16(fp, fvl, acc[nt], 0, 0, 0);
        }
        lacc = __builtin_amdgcn_mfma_f32_16x16x32_bf16(fp, ones, lacc, 0, 0, 0);
    }
#pragma unroll
    for (int r = 0; r < 4; r++) {
        int s = s0 + wave * 16 + q * 4 + r;
        float inv = 1.0f / lacc[r];
        size_t off = ((size_t)(b * SEQ + s)) * DMODEL + h * 64;
#pragma unroll
        for (int nt = 0; nt < 4; nt++) {
            int d = nt * 16 + l15;
            ushort hs, ls;
            split1(acc[nt][r] * inv, hs, ls);
            ctxh[off + d] = hs;
            ctxl[off + d] = ls;
        }
    }
}

extern "C" void kernel_launch(void* const* d_in, const int* in_sizes, int n_in,
                              void* d_out, int out_size, void* d_ws, size_t ws_size,
                              hipStream_t stream) {
    const float* x    = (const float*)d_in[0];
    const float* Wqkv = (const float*)d_in[1];
    const float* bqkv = (const float*)d_in[2];
    const float* Wout = (const float*)d_in[3];
    const float* bout = (const float*)d_in[4];
    float* out = (float*)d_out;

    char* ws = (char*)d_ws;
    // persistent layout
    ushort* Qh  = (ushort*)(ws + 0);                 //  6,291,456
    ushort* Ql  = (ushort*)(ws + 6291456);
    ushort* Kh  = (ushort*)(ws + 12582912);
    ushort* Kl  = (ushort*)(ws + 18874368);
    ushort* Vth = (ushort*)(ws + 25165824);
    ushort* Vtl = (ushort*)(ws + 31457280);          // ends 37,748,736
    float*  S   = (float*)(ws + 37748736);           // 201,326,592 -> ends 239,075,328
    ushort* ctxh = (ushort*)(ws + 239075328);        //  6,291,456
    ushort* ctxl = (ushort*)(ws + 245366784);        // ends 251,658,240
    unsigned* hist   = (unsigned*)(ws + 251658240);  // 48*2048*4 = 393,216 -> ends 252,051,456
    unsigned* prefix = (unsigned*)(ws + 252051456);  // 192
    unsigned* krem   = (unsigned*)(ws + 252051648);  // 192
    unsigned* cnt    = (unsigned*)(ws + 252051840);  // 192
    float*    thr    = (float*)(ws + 252052032);     // 192 -> ends 252,052,224
    // overlays: x/W splits live in S region (dead until k_scores_mfma)
    ushort* xh     = (ushort*)(ws + 37748736);                // 6,291,456
    ushort* xl     = (ushort*)(ws + 37748736 + 6291456);      // 6,291,456
    ushort* Wqkvth = (ushort*)(ws + 37748736 + 12582912);     // 3,538,944
    ushort* Wqkvtl = (ushort*)(ws + 37748736 + 16121856);     // ends +19,660,800
    // cand overlays Qh..Kl (dead after scores): 48*131072*4 = 25,165,824
    float* cand = (float*)(ws + 0);
    // Wout split overlays S (dead after k_pv)
    ushort* Woutth = (ushort*)(ws + 37748736);                // 1,179,648
    ushort* Wouttl = (ushort*)(ws + 37748736 + 1179648);

    k_init<<<384, 256, 0, stream>>>(hist, cnt);
    k_xsplit<<<NTOK * DMODEL / 1024, 256, 0, stream>>>(x, xh, xl, NTOK * DMODEL);
    k_wsplit<<<dim3(D3 / 64, DMODEL / 64), 256, 0, stream>>>(Wqkv, Wqkvth, Wqkvtl, DMODEL, D3);
    // QKV GEMM -> split Q/K straight, V transposed
    k_gemm_qkv<<<dim3(D3 / 128, NTOK / 128), 256, 0, stream>>>(
        xh, xl, Wqkvth, Wqkvtl, bqkv, Qh, Ql, Kh, Kl, Vth, Vtl);
    // scores (MFMA) + fused 11-bit histogram
    k_scores_mfma<<<dim3(8, 8, BH), 256, 0, stream>>>(Qh, Ql, Kh, Kl, S, hist);
    k_select0<<<BH, 256, 0, stream>>>(hist, prefix, krem);
    // compact matching ~10% + 8-bit hist (bits 20:13)
    k_compact<<<dim3(256, BH), 256, 0, stream>>>(S, prefix, hist, cnt, cand);
    k_select<<<1, 64, 0, stream>>>(hist, prefix, krem, thr, 13, 256, 0);
    // bits 12:5 on candidates
    k_candhist<<<dim3(32, BH), 256, 0, stream>>>(cand, cnt, prefix, hist, 13, 5, 255u);
    k_select<<<1, 64, 0, stream>>>(hist, prefix, krem, thr, 5, 256, 0);
    // bits 4:0 on candidates
    k_candhist<<<dim3(32, BH), 256, 0, stream>>>(cand, cnt, prefix, hist, 5, 0, 31u);
    k_select<<<1, 64, 0, stream>>>(hist, prefix, krem, thr, 0, 32, 1);
    // PV (MFMA) -> ctx split bf16
    k_pv<<<dim3(16, BH), 256, 0, stream>>>(S, Vth, Vtl, thr, ctxh, ctxl);
    // out = ctx @ W_out + b_out
    k_wsplit<<<dim3(DMODEL / 64, DMODEL / 64), 256, 0, stream>>>(Wout, Woutth, Wouttl, DMODEL, DMODEL);
    k_gemm_mfma<<<dim3(DMODEL / 128, NTOK / 128), 256, 0, stream>>>(
        ctxh, ctxl, Woutth, Wouttl, bout, out, NTOK, DMODEL, DMODEL);
}

// Round 4
// 395.489 us; speedup vs baseline: 2.0936x; 1.3283x over previous
//
#include <hip/hip_runtime.h>
#include <math.h>

#define SEQ 1024
#define DMODEL 768
#define NHEADS 12
#define HDIM 64
#define D3 2304
#define BH 48            // BATCH*NHEADS
#define NTOK 4096        // BATCH*SEQ
#define NN (SEQ*SEQ)     // 1048576
#define KTH 104857u      // int(1024*1024*0.1)

typedef __bf16 bf16x8 __attribute__((ext_vector_type(8)));
typedef float  f32x4  __attribute__((ext_vector_type(4)));

// ---------------- fp32 -> (bf16 hi, bf16 lo) split, RNE ----------------
__device__ __forceinline__ void split1(float x, ushort& h, ushort& l) {
    unsigned b  = __float_as_uint(x);
    unsigned hb = (b + 0x7FFFu + ((b >> 16) & 1u)) >> 16;   // RNE to bf16
    float hf = __uint_as_float(hb << 16);
    float r  = x - hf;
    unsigned rb = __float_as_uint(r);
    unsigned lb = (rb + 0x7FFFu + ((rb >> 16) & 1u)) >> 16;
    h = (ushort)hb; l = (ushort)lb;
}

__device__ __forceinline__ ushort bf16rne(float x) {
    unsigned b = __float_as_uint(x);
    return (ushort)((b + 0x7FFFu + ((b >> 16) & 1u)) >> 16);
}

// ---------------- init: zero histograms ----------------
__global__ void k_init(unsigned* __restrict__ hist) {
    int t = blockIdx.x * 256 + threadIdx.x;
    if (t < BH * 2048) hist[t] = 0u;
}

// ---------------- elementwise split: x -> xh, xl ----------------
__global__ __launch_bounds__(256) void k_xsplit(const float* __restrict__ x,
                                                ushort* __restrict__ xh,
                                                ushort* __restrict__ xl, int n) {
    int i = (blockIdx.x * 256 + threadIdx.x) * 4;
    if (i >= n) return;
    float4 v = *(const float4*)(x + i);
    ushort4 h, l;
    split1(v.x, h.x, l.x); split1(v.y, h.y, l.y);
    split1(v.z, h.z, l.z); split1(v.w, h.w, l.w);
    *(ushort4*)(xh + i) = h;
    *(ushort4*)(xl + i) = l;
}

// ---------------- transpose + split: W[K][N] -> Wt_h/Wt_l [N][K] ----------------
__global__ __launch_bounds__(256) void k_wsplit(const float* __restrict__ W,
                                                ushort* __restrict__ Wth,
                                                ushort* __restrict__ Wtl,
                                                int K, int N) {
    __shared__ float t[64][65];
    int k0 = blockIdx.y * 64, n0 = blockIdx.x * 64;
    int tid = threadIdx.x;
    int r = tid >> 4, c = (tid & 15) * 4;
#pragma unroll
    for (int u = 0; u < 4; u++) {
        int rr = r + u * 16;
        float4 v = *(const float4*)(W + (size_t)(k0 + rr) * N + n0 + c);
        t[rr][c] = v.x; t[rr][c + 1] = v.y; t[rr][c + 2] = v.z; t[rr][c + 3] = v.w;
    }
    __syncthreads();
    int n = tid >> 2, kc = (tid & 3) * 16;
    ushort hb[16] __attribute__((aligned(16)));
    ushort lb[16] __attribute__((aligned(16)));
#pragma unroll
    for (int j = 0; j < 16; j++) split1(t[kc + j][n], hb[j], lb[j]);
    ushort* dh = Wth + (size_t)(n0 + n) * K + k0 + kc;
    ushort* dl = Wtl + (size_t)(n0 + n) * K + k0 + kc;
    *(uint4*)(dh)     = *(uint4*)&hb[0];
    *(uint4*)(dh + 8) = *(uint4*)&hb[8];
    *(uint4*)(dl)     = *(uint4*)&lb[0];
    *(uint4*)(dl + 8) = *(uint4*)&lb[8];
}

// ---------------- bf16x3 MFMA GEMM: C = A@B + bias (fp32 out) ----------------
#define LDK 40
__global__ __launch_bounds__(256) void k_gemm_mfma(
    const ushort* __restrict__ Ah, const ushort* __restrict__ Al,
    const ushort* __restrict__ Bh, const ushort* __restrict__ Bl,
    const float* __restrict__ bias, float* __restrict__ C,
    int M, int N, int K) {
    __shared__ ushort sAh[128 * LDK], sAl[128 * LDK];
    __shared__ ushort sBh[128 * LDK], sBl[128 * LDK];
    int tid = threadIdx.x;
    int lane = tid & 63;
    int wave = tid >> 6;
    int wm = (wave >> 1) * 64, wn = (wave & 1) * 64;
    int m0 = blockIdx.y * 128, n0 = blockIdx.x * 128;
    int l15 = lane & 15, q = lane >> 4;

    int srow = tid >> 2;
    int schunk = (tid & 3) * 8;
    const ushort* gAh = Ah + (size_t)(m0 + srow) * K + schunk;
    const ushort* gAl = Al + (size_t)(m0 + srow) * K + schunk;
    const ushort* gBh = Bh + (size_t)(n0 + srow) * K + schunk;
    const ushort* gBl = Bl + (size_t)(n0 + srow) * K + schunk;
    size_t rstep = (size_t)64 * K;

    int woffA = srow * LDK + schunk;
    int woffA2 = (srow + 64) * LDK + schunk;

    f32x4 acc[4][4] = {};

    for (int k0 = 0; k0 < K; k0 += 32) {
        uint4 a0 = *(const uint4*)(gAh + k0);
        uint4 a1 = *(const uint4*)(gAh + rstep + k0);
        uint4 a2 = *(const uint4*)(gAl + k0);
        uint4 a3 = *(const uint4*)(gAl + rstep + k0);
        uint4 b0 = *(const uint4*)(gBh + k0);
        uint4 b1 = *(const uint4*)(gBh + rstep + k0);
        uint4 b2 = *(const uint4*)(gBl + k0);
        uint4 b3 = *(const uint4*)(gBl + rstep + k0);
        __syncthreads();
        *(uint4*)(sAh + woffA)  = a0;
        *(uint4*)(sAh + woffA2) = a1;
        *(uint4*)(sAl + woffA)  = a2;
        *(uint4*)(sAl + woffA2) = a3;
        *(uint4*)(sBh + woffA)  = b0;
        *(uint4*)(sBh + woffA2) = b1;
        *(uint4*)(sBl + woffA)  = b2;
        *(uint4*)(sBl + woffA2) = b3;
        __syncthreads();
        bf16x8 fah[4], fal[4], fbh[4], fbl[4];
#pragma unroll
        for (int mt = 0; mt < 4; mt++) {
            int off = (wm + mt * 16 + l15) * LDK + q * 8;
            fah[mt] = *(const bf16x8*)(sAh + off);
            fal[mt] = *(const bf16x8*)(sAl + off);
        }
#pragma unroll
        for (int nt = 0; nt < 4; nt++) {
            int off = (wn + nt * 16 + l15) * LDK + q * 8;
            fbh[nt] = *(const bf16x8*)(sBh + off);
            fbl[nt] = *(const bf16x8*)(sBl + off);
        }
#pragma unroll
        for (int mt = 0; mt < 4; mt++)
#pragma unroll
            for (int nt = 0; nt < 4; nt++) {
                acc[mt][nt] = __builtin_amdgcn_mfma_f32_16x16x32_bf16(
                    fah[mt], fbh[nt], acc[mt][nt], 0, 0, 0);
                acc[mt][nt] = __builtin_amdgcn_mfma_f32_16x16x32_bf16(
                    fah[mt], fbl[nt], acc[mt][nt], 0, 0, 0);
                acc[mt][nt] = __builtin_amdgcn_mfma_f32_16x16x32_bf16(
                    fal[mt], fbh[nt], acc[mt][nt], 0, 0, 0);
            }
    }
#pragma unroll
    for (int nt = 0; nt < 4; nt++) {
        int col = n0 + wn + nt * 16 + l15;
        float bv = bias[col];
#pragma unroll
        for (int mt = 0; mt < 4; mt++) {
            int rowb = m0 + wm + mt * 16 + q * 4;
#pragma unroll
            for (int r = 0; r < 4; r++)
                C[(size_t)(rowb + r) * N + col] = acc[mt][nt][r] + bv;
        }
    }
}

// ---------------- QKV GEMM: epilogue writes split Q/K straight + V transposed ---
__global__ __launch_bounds__(256) void k_gemm_qkv(
    const ushort* __restrict__ Ah, const ushort* __restrict__ Al,
    const ushort* __restrict__ Bh, const ushort* __restrict__ Bl,
    const float* __restrict__ bias,
    ushort* __restrict__ Qh, ushort* __restrict__ Ql,
    ushort* __restrict__ Kh, ushort* __restrict__ Kl,
    ushort* __restrict__ Vth, ushort* __restrict__ Vtl) {
    const int N = D3, K = DMODEL;
    __shared__ ushort sAh[128 * LDK], sAl[128 * LDK];
    __shared__ ushort sBh[128 * LDK], sBl[128 * LDK];
    int tid = threadIdx.x;
    int lane = tid & 63;
    int wave = tid >> 6;
    int wm = (wave >> 1) * 64, wn = (wave & 1) * 64;
    int m0 = blockIdx.y * 128, n0 = blockIdx.x * 128;
    int l15 = lane & 15, q = lane >> 4;

    int srow = tid >> 2;
    int schunk = (tid & 3) * 8;
    const ushort* gAh = Ah + (size_t)(m0 + srow) * K + schunk;
    const ushort* gAl = Al + (size_t)(m0 + srow) * K + schunk;
    const ushort* gBh = Bh + (size_t)(n0 + srow) * K + schunk;
    const ushort* gBl = Bl + (size_t)(n0 + srow) * K + schunk;
    size_t rstep = (size_t)64 * K;
    int woffA = srow * LDK + schunk;
    int woffA2 = (srow + 64) * LDK + schunk;

    f32x4 acc[4][4] = {};
    for (int k0 = 0; k0 < K; k0 += 32) {
        uint4 a0 = *(const uint4*)(gAh + k0);
        uint4 a1 = *(const uint4*)(gAh + rstep + k0);
        uint4 a2 = *(const uint4*)(gAl + k0);
        uint4 a3 = *(const uint4*)(gAl + rstep + k0);
        uint4 b0 = *(const uint4*)(gBh + k0);
        uint4 b1 = *(const uint4*)(gBh + rstep + k0);
        uint4 b2 = *(const uint4*)(gBl + k0);
        uint4 b3 = *(const uint4*)(gBl + rstep + k0);
        __syncthreads();
        *(uint4*)(sAh + woffA)  = a0;
        *(uint4*)(sAh + woffA2) = a1;
        *(uint4*)(sAl + woffA)  = a2;
        *(uint4*)(sAl + woffA2) = a3;
        *(uint4*)(sBh + woffA)  = b0;
        *(uint4*)(sBh + woffA2) = b1;
        *(uint4*)(sBl + woffA)  = b2;
        *(uint4*)(sBl + woffA2) = b3;
        __syncthreads();
        bf16x8 fah[4], fal[4], fbh[4], fbl[4];
#pragma unroll
        for (int mt = 0; mt < 4; mt++) {
            int off = (wm + mt * 16 + l15) * LDK + q * 8;
            fah[mt] = *(const bf16x8*)(sAh + off);
            fal[mt] = *(const bf16x8*)(sAl + off);
        }
#pragma unroll
        for (int nt = 0; nt < 4; nt++) {
            int off = (wn + nt * 16 + l15) * LDK + q * 8;
            fbh[nt] = *(const bf16x8*)(sBh + off);
            fbl[nt] = *(const bf16x8*)(sBl + off);
        }
#pragma unroll
        for (int mt = 0; mt < 4; mt++)
#pragma unroll
            for (int nt = 0; nt < 4; nt++) {
                acc[mt][nt] = __builtin_amdgcn_mfma_f32_16x16x32_bf16(
                    fah[mt], fbh[nt], acc[mt][nt], 0, 0, 0);
                acc[mt][nt] = __builtin_amdgcn_mfma_f32_16x16x32_bf16(
                    fah[mt], fbl[nt], acc[mt][nt], 0, 0, 0);
                acc[mt][nt] = __builtin_amdgcn_mfma_f32_16x16x32_bf16(
                    fal[mt], fbh[nt], acc[mt][nt], 0, 0, 0);
            }
    }
    int region = n0 / 768;    // 0=Q, 1=K, 2=V
    int b = m0 >> 10;
#pragma unroll
    for (int nt = 0; nt < 4; nt++) {
        int col = n0 + wn + nt * 16 + l15;
        float bv = bias[col];
        int cin = col - region * 768;
        int h = cin >> 6, d = cin & 63;
        int bh = b * NHEADS + h;
#pragma unroll
        for (int mt = 0; mt < 4; mt++) {
            int s0 = (m0 + wm + mt * 16 + q * 4) & 1023;
            if (region == 2) {
                ushort h4[4] __attribute__((aligned(8)));
                ushort l4[4] __attribute__((aligned(8)));
#pragma unroll
                for (int r = 0; r < 4; r++)
                    split1(acc[mt][nt][r] + bv, h4[r], l4[r]);
                size_t off = ((size_t)(bh * 64 + d) << 10) + s0;
                *(ushort4*)(Vth + off) = *(ushort4*)h4;
                *(ushort4*)(Vtl + off) = *(ushort4*)l4;
            } else {
                ushort* Ph = region ? Kh : Qh;
                ushort* Pl = region ? Kl : Ql;
                size_t off = ((size_t)((bh << 10) + s0)) * 64 + d;
#pragma unroll
                for (int r = 0; r < 4; r++) {
                    ushort hs, ls;
                    split1(acc[mt][nt][r] + bv, hs, ls);
                    Ph[off + (size_t)r * 64] = hs;
                    Pl[off + (size_t)r * 64] = ls;
                }
            }
        }
    }
}

// ---------------- scores: P[bh,i,j] = bf16(exp(q_i.k_j/8)) + 11-bit hist -------
// grid (8, 8, 48). Direct-global Q/K fragments; LDS used for P transpose + hist.
__global__ __launch_bounds__(256) void k_scores(
    const ushort* __restrict__ Qh, const ushort* __restrict__ Ql,
    const ushort* __restrict__ Kh, const ushort* __restrict__ Kl,
    ushort* __restrict__ P, unsigned* __restrict__ hist) {
    __shared__ ushort sP[128 * 132];
    __shared__ unsigned lh[2048];
    int bh = blockIdx.z;
    int i0 = blockIdx.y * 128, j0 = blockIdx.x * 128;
    int tid = threadIdx.x, lane = tid & 63, wave = tid >> 6;
    int l15 = lane & 15, q = lane >> 4;
    int wm = (wave >> 1) * 64, wn = (wave & 1) * 64;
    for (int i = tid; i < 2048; i += 256) lh[i] = 0u;

    const ushort* qb  = Qh + (((size_t)bh << 10)) * 64;
    const ushort* qlb = Ql + (((size_t)bh << 10)) * 64;
    const ushort* kb  = Kh + (((size_t)bh << 10)) * 64;
    const ushort* klb = Kl + (((size_t)bh << 10)) * 64;

    f32x4 acc[4][4] = {};
#pragma unroll
    for (int kk = 0; kk < 64; kk += 32) {
        bf16x8 fqh[4], fql[4], fkh[4], fkl[4];
#pragma unroll
        for (int mt = 0; mt < 4; mt++) {
            size_t off = (size_t)(i0 + wm + mt * 16 + l15) * 64 + kk + q * 8;
            fqh[mt] = *(const bf16x8*)(qb + off);
            fql[mt] = *(const bf16x8*)(qlb + off);
        }
#pragma unroll
        for (int nt = 0; nt < 4; nt++) {
            size_t off = (size_t)(j0 + wn + nt * 16 + l15) * 64 + kk + q * 8;
            fkh[nt] = *(const bf16x8*)(kb + off);
            fkl[nt] = *(const bf16x8*)(klb + off);
        }
#pragma unroll
        for (int mt = 0; mt < 4; mt++)
#pragma unroll
            for (int nt = 0; nt < 4; nt++) {
                acc[mt][nt] = __builtin_amdgcn_mfma_f32_16x16x32_bf16(
                    fqh[mt], fkh[nt], acc[mt][nt], 0, 0, 0);
                acc[mt][nt] = __builtin_amdgcn_mfma_f32_16x16x32_bf16(
                    fqh[mt], fkl[nt], acc[mt][nt], 0, 0, 0);
                acc[mt][nt] = __builtin_amdgcn_mfma_f32_16x16x32_bf16(
                    fql[mt], fkh[nt], acc[mt][nt], 0, 0, 0);
            }
    }
    __syncthreads();   // lh zeroed by all
    // epilogue: p = bf16(exp(s/8)); LDS scatter (transpose) + histogram
#pragma unroll
    for (int mt = 0; mt < 4; mt++)
#pragma unroll
        for (int nt = 0; nt < 4; nt++) {
            int jj = wn + nt * 16 + l15;
            int ib = wm + mt * 16 + q * 4;
#pragma unroll
            for (int r2 = 0; r2 < 4; r2++) {
                ushort pb = bf16rne(__expf(acc[mt][nt][r2] * 0.125f));
                sP[(ib + r2) * 132 + jj] = pb;
                atomicAdd(&lh[pb >> 5], 1u);
            }
        }
    __syncthreads();
    // coalesced write-out: 2 threads per row
    int rloc = tid >> 1;
    int ch = (tid & 1) * 64;
    ushort* dst = P + ((size_t)bh << 20) + (size_t)(i0 + rloc) * 1024 + j0 + ch;
    const ushort* src = sP + rloc * 132 + ch;
#pragma unroll
    for (int c = 0; c < 8; c++)
        *(uint4*)(dst + c * 8) = *(const uint4*)(src + c * 8);
    for (int i = tid; i < 2048; i += 256) {
        unsigned cc = lh[i];
        if (cc) atomicAdd(&hist[bh * 2048 + i], cc);
    }
}

// ---------------- select0: 2048-bin scan, one block per bh; resets hist --------
__global__ void k_select0(unsigned* __restrict__ hist, unsigned* __restrict__ prefix,
                          unsigned* __restrict__ krem) {
    int bh = blockIdx.x;
    unsigned* hrow = hist + bh * 2048;
    __shared__ unsigned ps[256];
    __shared__ unsigned sdig, sbelow;
    int tid = threadIdx.x;
    unsigned s = 0;
#pragma unroll
    for (int i = 0; i < 8; i++) s += hrow[tid * 8 + i];
    ps[tid] = s;
    __syncthreads();
    if (tid == 0) {
        unsigned k = KTH, run = 0; int chunk = 255;
        for (int t2 = 0; t2 < 256; t2++) {
            if (run + ps[t2] >= k) { chunk = t2; break; }
            run += ps[t2];
        }
        int d = 7;
        for (int i = 0; i < 8; i++) {
            unsigned v = hrow[chunk * 8 + i];
            if (run + v >= k) { d = i; break; }
            run += v;
        }
        sdig = (unsigned)(chunk * 8 + d); sbelow = run;
    }
    __syncthreads();
#pragma unroll
    for (int i = 0; i < 8; i++) hrow[tid * 8 + i] = 0u;
    if (tid == 0) { prefix[bh] = sdig; krem[bh] = KTH - sbelow; }
}

// ---------------- hist2: stream P, 32-bin hist among 11-bit-prefix matches -----
// grid (64, 48): each block 16384 elems
__global__ __launch_bounds__(256) void k_hist2(const ushort* __restrict__ P,
                                               const unsigned* __restrict__ prefix,
                                               unsigned* __restrict__ hist) {
    __shared__ unsigned lh[32];
    int tid = threadIdx.x;
    if (tid < 32) lh[tid] = 0u;
    __syncthreads();
    int bh = blockIdx.y;
    unsigned pm = prefix[bh];
    const ushort* pb = P + ((size_t)bh << 20) + (size_t)blockIdx.x * 16384;
#pragma unroll
    for (int it = 0; it < 8; it++) {
        uint4 v = *(const uint4*)(pb + it * 2048 + tid * 8);
        unsigned w[4] = {v.x, v.y, v.z, v.w};
#pragma unroll
        for (int e = 0; e < 4; e++) {
            unsigned lo = w[e] & 0xFFFFu, hi = w[e] >> 16;
            if ((lo >> 5) == pm) atomicAdd(&lh[lo & 31u], 1u);
            if ((hi >> 5) == pm) atomicAdd(&lh[hi & 31u], 1u);
        }
    }
    __syncthreads();
    if (tid < 32) {
        unsigned c = lh[tid];
        if (c) atomicAdd(&hist[bh * 2048 + tid], c);
    }
}

// ---------------- final select: 32 bins -> bf16 threshold bit pattern ----------
__global__ void k_selectF(const unsigned* __restrict__ hist,
                          const unsigned* __restrict__ prefix,
                          const unsigned* __restrict__ krem,
                          unsigned* __restrict__ thrb) {
    int bh = threadIdx.x;
    if (bh >= BH) return;
    const unsigned* hrow = hist + bh * 2048;
    unsigned k = krem[bh], run = 0;
    int d = 31;
    for (int i = 0; i < 32; i++) {
        unsigned c = hrow[i];
        if (run + c >= k) { d = i; break; }
        run += c;
    }
    thrb[bh] = (prefix[bh] << 5) | (unsigned)d;
}

// ---------------- PV: ctx = (masked P) @ V / rowsum, all direct-global ---------
// grid (16, 48): 4 waves x 16 rows; no LDS, no syncthreads.
__global__ __launch_bounds__(256) void k_pv(const ushort* __restrict__ P,
                                            const ushort* __restrict__ Vth,
                                            const ushort* __restrict__ Vtl,
                                            const unsigned* __restrict__ thrb,
                                            ushort* __restrict__ ctxh,
                                            ushort* __restrict__ ctxl) {
    int bh = blockIdx.y;
    int b = bh / NHEADS, h = bh % NHEADS;
    int lane = threadIdx.x & 63, wave = threadIdx.x >> 6;
    int l15 = lane & 15, q = lane >> 4;
    int ibase = blockIdx.x * 64 + wave * 16;
    unsigned t = thrb[bh];
    const ushort* prow = P + ((size_t)bh << 20) + (size_t)(ibase + l15) * 1024 + q * 8;
    const ushort* vh0 = Vth + ((size_t)bh << 16);   // [64][1024]
    const ushort* vl0 = Vtl + ((size_t)bh << 16);
    f32x4 acc[4] = {};
    f32x4 lacc = {};
    uint4 onesu = {0x3F803F80u, 0x3F803F80u, 0x3F803F80u, 0x3F803F80u};
    bf16x8 ones = *(bf16x8*)&onesu;
    for (int j0 = 0; j0 < SEQ; j0 += 32) {
        uint4 a = *(const uint4*)(prow + j0);
        unsigned* w = (unsigned*)&a;
#pragma unroll
        for (int e = 0; e < 4; e++) {
            unsigned lo = w[e] & 0xFFFFu, hi = w[e] >> 16;
            lo = (lo <= t) ? 0u : lo;
            hi = (hi <= t) ? 0u : hi;
            w[e] = lo | (hi << 16);
        }
        bf16x8 pa = *(bf16x8*)&a;
#pragma unroll
        for (int nt = 0; nt < 4; nt++) {
            size_t off = (size_t)(nt * 16 + l15) * 1024 + j0 + q * 8;
            bf16x8 fvh = *(const bf16x8*)(vh0 + off);
            bf16x8 fvl = *(const bf16x8*)(vl0 + off);
            acc[nt] = __builtin_amdgcn_mfma_f32_16x16x32_bf16(pa, fvh, acc[nt], 0, 0, 0);
            acc[nt] = __builtin_amdgcn_mfma_f32_16x16x32_bf16(pa, fvl, acc[nt], 0, 0, 0);
        }
        lacc = __builtin_amdgcn_mfma_f32_16x16x32_bf16(pa, ones, lacc, 0, 0, 0);
    }
#pragma unroll
    for (int r = 0; r < 4; r++) {
        int i = ibase + q * 4 + r;
        float inv = 1.0f / lacc[r];
        size_t off = ((size_t)(b * SEQ + i)) * DMODEL + h * 64;
#pragma unroll
        for (int nt = 0; nt < 4; nt++) {
            int d = nt * 16 + l15;
            ushort hs, ls;
            split1(acc[nt][r] * inv, hs, ls);
            ctxh[off + d] = hs;
            ctxl[off + d] = ls;
        }
    }
}

extern "C" void kernel_launch(void* const* d_in, const int* in_sizes, int n_in,
                              void* d_out, int out_size, void* d_ws, size_t ws_size,
                              hipStream_t stream) {
    const float* x    = (const float*)d_in[0];
    const float* Wqkv = (const float*)d_in[1];
    const float* bqkv = (const float*)d_in[2];
    const float* Wout = (const float*)d_in[3];
    const float* bout = (const float*)d_in[4];
    float* out = (float*)d_out;

    char* ws = (char*)d_ws;
    // persistent layout
    ushort* Qh  = (ushort*)(ws + 0);                 //  6,291,456
    ushort* Ql  = (ushort*)(ws + 6291456);
    ushort* Kh  = (ushort*)(ws + 12582912);
    ushort* Kl  = (ushort*)(ws + 18874368);
    ushort* Vth = (ushort*)(ws + 25165824);
    ushort* Vtl = (ushort*)(ws + 31457280);          // ends 37,748,736
    ushort* P   = (ushort*)(ws + 37748736);          // 100,663,296 -> ends 138,412,032
    ushort* ctxh = (ushort*)(ws + 239075328);        //  6,291,456
    ushort* ctxl = (ushort*)(ws + 245366784);        // ends 251,658,240
    unsigned* hist   = (unsigned*)(ws + 251658240);  // 393,216
    unsigned* prefix = (unsigned*)(ws + 252051456);  // 192
    unsigned* krem   = (unsigned*)(ws + 252051648);  // 192
    unsigned* thrb   = (unsigned*)(ws + 252051840);  // 192
    // overlays inside P region (dead until k_scores writes P):
    ushort* xh     = (ushort*)(ws + 37748736);
    ushort* xl     = (ushort*)(ws + 37748736 + 6291456);
    ushort* Wqkvth = (ushort*)(ws + 37748736 + 12582912);
    ushort* Wqkvtl = (ushort*)(ws + 37748736 + 16121856);
    // Wout split overlays P (dead after k_pv):
    ushort* Woutth = (ushort*)(ws + 37748736);
    ushort* Wouttl = (ushort*)(ws + 37748736 + 1179648);

    k_init<<<384, 256, 0, stream>>>(hist);
    k_xsplit<<<NTOK * DMODEL / 1024, 256, 0, stream>>>(x, xh, xl, NTOK * DMODEL);
    k_wsplit<<<dim3(D3 / 64, DMODEL / 64), 256, 0, stream>>>(Wqkv, Wqkvth, Wqkvtl, DMODEL, D3);
    k_gemm_qkv<<<dim3(D3 / 128, NTOK / 128), 256, 0, stream>>>(
        xh, xl, Wqkvth, Wqkvtl, bqkv, Qh, Ql, Kh, Kl, Vth, Vtl);
    // P = bf16(exp(QK^T/8)) + fused 11-bit histogram
    k_scores<<<dim3(8, 8, BH), 256, 0, stream>>>(Qh, Ql, Kh, Kl, P, hist);
    k_select0<<<BH, 256, 0, stream>>>(hist, prefix, krem);
    // exact bf16 threshold: one streaming pass, 32-bin
    k_hist2<<<dim3(64, BH), 256, 0, stream>>>(P, prefix, hist);
    k_selectF<<<1, 64, 0, stream>>>(hist, prefix, krem, thrb);
    // ctx = masked-softmax(P) @ V
    k_pv<<<dim3(16, BH), 256, 0, stream>>>(P, Vth, Vtl, thrb, ctxh, ctxl);
    // out = ctx @ W_out + b_out
    k_wsplit<<<dim3(DMODEL / 64, DMODEL / 64), 256, 0, stream>>>(Wout, Woutth, Wouttl, DMODEL, DMODEL);
    k_gemm_mfma<<<dim3(DMODEL / 128, NTOK / 128), 256, 0, stream>>>(
        ctxh, ctxl, Woutth, Wouttl, bout, out, NTOK, DMODEL, DMODEL);
}

// Round 5
// 354.040 us; speedup vs baseline: 2.3387x; 1.1171x over previous
//
#include <hip/hip_runtime.h>
#include <math.h>

#define SEQ 1024
#define DMODEL 768
#define NHEADS 12
#define HDIM 64
#define D3 2304
#define BH 48            // BATCH*NHEADS
#define NTOK 4096        // BATCH*SEQ
#define NN (SEQ*SEQ)     // 1048576
#define KTH 104857u      // int(1024*1024*0.1)

typedef __bf16 bf16x8 __attribute__((ext_vector_type(8)));
typedef float  f32x4  __attribute__((ext_vector_type(4)));

// ---------------- fp32 -> (bf16 hi, bf16 lo) split, RNE ----------------
__device__ __forceinline__ void split1(float x, ushort& h, ushort& l) {
    unsigned b  = __float_as_uint(x);
    unsigned hb = (b + 0x7FFFu + ((b >> 16) & 1u)) >> 16;   // RNE to bf16
    float hf = __uint_as_float(hb << 16);
    float r  = x - hf;
    unsigned rb = __float_as_uint(r);
    unsigned lb = (rb + 0x7FFFu + ((rb >> 16) & 1u)) >> 16;
    h = (ushort)hb; l = (ushort)lb;
}

__device__ __forceinline__ ushort bf16rne(float x) {
    unsigned b = __float_as_uint(x);
    return (ushort)((b + 0x7FFFu + ((b >> 16) & 1u)) >> 16);
}

// ---------------- init: zero histograms ----------------
__global__ void k_init(unsigned* __restrict__ hist) {
    int t = blockIdx.x * 256 + threadIdx.x;
    if (t < BH * 2048) hist[t] = 0u;
}

// ---------------- elementwise split: x -> xh, xl ----------------
__global__ __launch_bounds__(256) void k_xsplit(const float* __restrict__ x,
                                                ushort* __restrict__ xh,
                                                ushort* __restrict__ xl, int n) {
    int i = (blockIdx.x * 256 + threadIdx.x) * 4;
    if (i >= n) return;
    float4 v = *(const float4*)(x + i);
    ushort4 h, l;
    split1(v.x, h.x, l.x); split1(v.y, h.y, l.y);
    split1(v.z, h.z, l.z); split1(v.w, h.w, l.w);
    *(ushort4*)(xh + i) = h;
    *(ushort4*)(xl + i) = l;
}

// ---------------- transpose + split: W[K][N] -> Wt_h/Wt_l [N][K] ----------------
__global__ __launch_bounds__(256) void k_wsplit(const float* __restrict__ W,
                                                ushort* __restrict__ Wth,
                                                ushort* __restrict__ Wtl,
                                                int K, int N) {
    __shared__ float t[64][65];
    int k0 = blockIdx.y * 64, n0 = blockIdx.x * 64;
    int tid = threadIdx.x;
    int r = tid >> 4, c = (tid & 15) * 4;
#pragma unroll
    for (int u = 0; u < 4; u++) {
        int rr = r + u * 16;
        float4 v = *(const float4*)(W + (size_t)(k0 + rr) * N + n0 + c);
        t[rr][c] = v.x; t[rr][c + 1] = v.y; t[rr][c + 2] = v.z; t[rr][c + 3] = v.w;
    }
    __syncthreads();
    int n = tid >> 2, kc = (tid & 3) * 16;
    ushort hb[16] __attribute__((aligned(16)));
    ushort lb[16] __attribute__((aligned(16)));
#pragma unroll
    for (int j = 0; j < 16; j++) split1(t[kc + j][n], hb[j], lb[j]);
    ushort* dh = Wth + (size_t)(n0 + n) * K + k0 + kc;
    ushort* dl = Wtl + (size_t)(n0 + n) * K + k0 + kc;
    *(uint4*)(dh)     = *(uint4*)&hb[0];
    *(uint4*)(dh + 8) = *(uint4*)&hb[8];
    *(uint4*)(dl)     = *(uint4*)&lb[0];
    *(uint4*)(dl + 8) = *(uint4*)&lb[8];
}

// ---------------- bf16x3 MFMA GEMM: C = A@B + bias (fp32 out) ----------------
#define LDK 40
__global__ __launch_bounds__(256) void k_gemm_mfma(
    const ushort* __restrict__ Ah, const ushort* __restrict__ Al,
    const ushort* __restrict__ Bh, const ushort* __restrict__ Bl,
    const float* __restrict__ bias, float* __restrict__ C,
    int M, int N, int K) {
    __shared__ ushort sAh[128 * LDK], sAl[128 * LDK];
    __shared__ ushort sBh[128 * LDK], sBl[128 * LDK];
    int tid = threadIdx.x;
    int lane = tid & 63;
    int wave = tid >> 6;
    int wm = (wave >> 1) * 64, wn = (wave & 1) * 64;
    int m0 = blockIdx.y * 128, n0 = blockIdx.x * 128;
    int l15 = lane & 15, q = lane >> 4;

    int srow = tid >> 2;
    int schunk = (tid & 3) * 8;
    const ushort* gAh = Ah + (size_t)(m0 + srow) * K + schunk;
    const ushort* gAl = Al + (size_t)(m0 + srow) * K + schunk;
    const ushort* gBh = Bh + (size_t)(n0 + srow) * K + schunk;
    const ushort* gBl = Bl + (size_t)(n0 + srow) * K + schunk;
    size_t rstep = (size_t)64 * K;

    int woffA = srow * LDK + schunk;
    int woffA2 = (srow + 64) * LDK + schunk;

    f32x4 acc[4][4] = {};

    for (int k0 = 0; k0 < K; k0 += 32) {
        uint4 a0 = *(const uint4*)(gAh + k0);
        uint4 a1 = *(const uint4*)(gAh + rstep + k0);
        uint4 a2 = *(const uint4*)(gAl + k0);
        uint4 a3 = *(const uint4*)(gAl + rstep + k0);
        uint4 b0 = *(const uint4*)(gBh + k0);
        uint4 b1 = *(const uint4*)(gBh + rstep + k0);
        uint4 b2 = *(const uint4*)(gBl + k0);
        uint4 b3 = *(const uint4*)(gBl + rstep + k0);
        __syncthreads();
        *(uint4*)(sAh + woffA)  = a0;
        *(uint4*)(sAh + woffA2) = a1;
        *(uint4*)(sAl + woffA)  = a2;
        *(uint4*)(sAl + woffA2) = a3;
        *(uint4*)(sBh + woffA)  = b0;
        *(uint4*)(sBh + woffA2) = b1;
        *(uint4*)(sBl + woffA)  = b2;
        *(uint4*)(sBl + woffA2) = b3;
        __syncthreads();
        bf16x8 fah[4], fal[4], fbh[4], fbl[4];
#pragma unroll
        for (int mt = 0; mt < 4; mt++) {
            int off = (wm + mt * 16 + l15) * LDK + q * 8;
            fah[mt] = *(const bf16x8*)(sAh + off);
            fal[mt] = *(const bf16x8*)(sAl + off);
        }
#pragma unroll
        for (int nt = 0; nt < 4; nt++) {
            int off = (wn + nt * 16 + l15) * LDK + q * 8;
            fbh[nt] = *(const bf16x8*)(sBh + off);
            fbl[nt] = *(const bf16x8*)(sBl + off);
        }
#pragma unroll
        for (int mt = 0; mt < 4; mt++)
#pragma unroll
            for (int nt = 0; nt < 4; nt++) {
                acc[mt][nt] = __builtin_amdgcn_mfma_f32_16x16x32_bf16(
                    fah[mt], fbh[nt], acc[mt][nt], 0, 0, 0);
                acc[mt][nt] = __builtin_amdgcn_mfma_f32_16x16x32_bf16(
                    fah[mt], fbl[nt], acc[mt][nt], 0, 0, 0);
                acc[mt][nt] = __builtin_amdgcn_mfma_f32_16x16x32_bf16(
                    fal[mt], fbh[nt], acc[mt][nt], 0, 0, 0);
            }
    }
#pragma unroll
    for (int nt = 0; nt < 4; nt++) {
        int col = n0 + wn + nt * 16 + l15;
        float bv = bias[col];
#pragma unroll
        for (int mt = 0; mt < 4; mt++) {
            int rowb = m0 + wm + mt * 16 + q * 4;
#pragma unroll
            for (int r = 0; r < 4; r++)
                C[(size_t)(rowb + r) * N + col] = acc[mt][nt][r] + bv;
        }
    }
}

// ---------------- QKV GEMM: epilogue writes split Q/K straight + V(hi) transposed
__global__ __launch_bounds__(256) void k_gemm_qkv(
    const ushort* __restrict__ Ah, const ushort* __restrict__ Al,
    const ushort* __restrict__ Bh, const ushort* __restrict__ Bl,
    const float* __restrict__ bias,
    ushort* __restrict__ Qh, ushort* __restrict__ Ql,
    ushort* __restrict__ Kh, ushort* __restrict__ Kl,
    ushort* __restrict__ Vth) {
    const int N = D3, K = DMODEL;
    __shared__ ushort sAh[128 * LDK], sAl[128 * LDK];
    __shared__ ushort sBh[128 * LDK], sBl[128 * LDK];
    int tid = threadIdx.x;
    int lane = tid & 63;
    int wave = tid >> 6;
    int wm = (wave >> 1) * 64, wn = (wave & 1) * 64;
    int m0 = blockIdx.y * 128, n0 = blockIdx.x * 128;
    int l15 = lane & 15, q = lane >> 4;

    int srow = tid >> 2;
    int schunk = (tid & 3) * 8;
    const ushort* gAh = Ah + (size_t)(m0 + srow) * K + schunk;
    const ushort* gAl = Al + (size_t)(m0 + srow) * K + schunk;
    const ushort* gBh = Bh + (size_t)(n0 + srow) * K + schunk;
    const ushort* gBl = Bl + (size_t)(n0 + srow) * K + schunk;
    size_t rstep = (size_t)64 * K;
    int woffA = srow * LDK + schunk;
    int woffA2 = (srow + 64) * LDK + schunk;

    f32x4 acc[4][4] = {};
    for (int k0 = 0; k0 < K; k0 += 32) {
        uint4 a0 = *(const uint4*)(gAh + k0);
        uint4 a1 = *(const uint4*)(gAh + rstep + k0);
        uint4 a2 = *(const uint4*)(gAl + k0);
        uint4 a3 = *(const uint4*)(gAl + rstep + k0);
        uint4 b0 = *(const uint4*)(gBh + k0);
        uint4 b1 = *(const uint4*)(gBh + rstep + k0);
        uint4 b2 = *(const uint4*)(gBl + k0);
        uint4 b3 = *(const uint4*)(gBl + rstep + k0);
        __syncthreads();
        *(uint4*)(sAh + woffA)  = a0;
        *(uint4*)(sAh + woffA2) = a1;
        *(uint4*)(sAl + woffA)  = a2;
        *(uint4*)(sAl + woffA2) = a3;
        *(uint4*)(sBh + woffA)  = b0;
        *(uint4*)(sBh + woffA2) = b1;
        *(uint4*)(sBl + woffA)  = b2;
        *(uint4*)(sBl + woffA2) = b3;
        __syncthreads();
        bf16x8 fah[4], fal[4], fbh[4], fbl[4];
#pragma unroll
        for (int mt = 0; mt < 4; mt++) {
            int off = (wm + mt * 16 + l15) * LDK + q * 8;
            fah[mt] = *(const bf16x8*)(sAh + off);
            fal[mt] = *(const bf16x8*)(sAl + off);
        }
#pragma unroll
        for (int nt = 0; nt < 4; nt++) {
            int off = (wn + nt * 16 + l15) * LDK + q * 8;
            fbh[nt] = *(const bf16x8*)(sBh + off);
            fbl[nt] = *(const bf16x8*)(sBl + off);
        }
#pragma unroll
        for (int mt = 0; mt < 4; mt++)
#pragma unroll
            for (int nt = 0; nt < 4; nt++) {
                acc[mt][nt] = __builtin_amdgcn_mfma_f32_16x16x32_bf16(
                    fah[mt], fbh[nt], acc[mt][nt], 0, 0, 0);
                acc[mt][nt] = __builtin_amdgcn_mfma_f32_16x16x32_bf16(
                    fah[mt], fbl[nt], acc[mt][nt], 0, 0, 0);
                acc[mt][nt] = __builtin_amdgcn_mfma_f32_16x16x32_bf16(
                    fal[mt], fbh[nt], acc[mt][nt], 0, 0, 0);
            }
    }
    int region = n0 / 768;    // 0=Q, 1=K, 2=V
    int b = m0 >> 10;
#pragma unroll
    for (int nt = 0; nt < 4; nt++) {
        int col = n0 + wn + nt * 16 + l15;
        float bv = bias[col];
        int cin = col - region * 768;
        int h = cin >> 6, d = cin & 63;
        int bh = b * NHEADS + h;
#pragma unroll
        for (int mt = 0; mt < 4; mt++) {
            int s0 = (m0 + wm + mt * 16 + q * 4) & 1023;
            if (region == 2) {
                ushort h4[4] __attribute__((aligned(8)));
#pragma unroll
                for (int r = 0; r < 4; r++)
                    h4[r] = bf16rne(acc[mt][nt][r] + bv);
                size_t off = ((size_t)(bh * 64 + d) << 10) + s0;
                *(ushort4*)(Vth + off) = *(ushort4*)h4;
            } else {
                ushort* Ph = region ? Kh : Qh;
                ushort* Pl = region ? Kl : Ql;
                size_t off = ((size_t)((bh << 10) + s0)) * 64 + d;
#pragma unroll
                for (int r = 0; r < 4; r++) {
                    ushort hs, ls;
                    split1(acc[mt][nt][r] + bv, hs, ls);
                    Ph[off + (size_t)r * 64] = hs;
                    Pl[off + (size_t)r * 64] = ls;
                }
            }
        }
    }
}

// ---------------- scores: P[bh,i,j] = bf16(exp(q_i.k_j/8)) + 11-bit hist -------
// grid (8, 8, 48). Direct-global Q/K fragments; LDS used for P transpose + hist.
__global__ __launch_bounds__(256) void k_scores(
    const ushort* __restrict__ Qh, const ushort* __restrict__ Ql,
    const ushort* __restrict__ Kh, const ushort* __restrict__ Kl,
    ushort* __restrict__ P, unsigned* __restrict__ hist) {
    __shared__ ushort sP[128 * 132];
    __shared__ unsigned lh[2048];
    int bh = blockIdx.z;
    int i0 = blockIdx.y * 128, j0 = blockIdx.x * 128;
    int tid = threadIdx.x, lane = tid & 63, wave = tid >> 6;
    int l15 = lane & 15, q = lane >> 4;
    int wm = (wave >> 1) * 64, wn = (wave & 1) * 64;
    for (int i = tid; i < 2048; i += 256) lh[i] = 0u;

    const ushort* qb  = Qh + (((size_t)bh << 10)) * 64;
    const ushort* qlb = Ql + (((size_t)bh << 10)) * 64;
    const ushort* kb  = Kh + (((size_t)bh << 10)) * 64;
    const ushort* klb = Kl + (((size_t)bh << 10)) * 64;

    f32x4 acc[4][4] = {};
#pragma unroll
    for (int kk = 0; kk < 64; kk += 32) {
        bf16x8 fqh[4], fql[4], fkh[4], fkl[4];
#pragma unroll
        for (int mt = 0; mt < 4; mt++) {
            size_t off = (size_t)(i0 + wm + mt * 16 + l15) * 64 + kk + q * 8;
            fqh[mt] = *(const bf16x8*)(qb + off);
            fql[mt] = *(const bf16x8*)(qlb + off);
        }
#pragma unroll
        for (int nt = 0; nt < 4; nt++) {
            size_t off = (size_t)(j0 + wn + nt * 16 + l15) * 64 + kk + q * 8;
            fkh[nt] = *(const bf16x8*)(kb + off);
            fkl[nt] = *(const bf16x8*)(klb + off);
        }
#pragma unroll
        for (int mt = 0; mt < 4; mt++)
#pragma unroll
            for (int nt = 0; nt < 4; nt++) {
                acc[mt][nt] = __builtin_amdgcn_mfma_f32_16x16x32_bf16(
                    fqh[mt], fkh[nt], acc[mt][nt], 0, 0, 0);
                acc[mt][nt] = __builtin_amdgcn_mfma_f32_16x16x32_bf16(
                    fqh[mt], fkl[nt], acc[mt][nt], 0, 0, 0);
                acc[mt][nt] = __builtin_amdgcn_mfma_f32_16x16x32_bf16(
                    fql[mt], fkh[nt], acc[mt][nt], 0, 0, 0);
            }
    }
    __syncthreads();   // lh zeroed by all
#pragma unroll
    for (int mt = 0; mt < 4; mt++)
#pragma unroll
        for (int nt = 0; nt < 4; nt++) {
            int jj = wn + nt * 16 + l15;
            int ib = wm + mt * 16 + q * 4;
#pragma unroll
            for (int r2 = 0; r2 < 4; r2++) {
                ushort pb = bf16rne(__expf(acc[mt][nt][r2] * 0.125f));
                sP[(ib + r2) * 132 + jj] = pb;
                atomicAdd(&lh[pb >> 5], 1u);
            }
        }
    __syncthreads();
    int rloc = tid >> 1;
    int ch = (tid & 1) * 64;
    ushort* dst = P + ((size_t)bh << 20) + (size_t)(i0 + rloc) * 1024 + j0 + ch;
    const ushort* src = sP + rloc * 132 + ch;
#pragma unroll
    for (int c = 0; c < 8; c++)
        *(uint4*)(dst + c * 8) = *(const uint4*)(src + c * 8);
    for (int i = tid; i < 2048; i += 256) {
        unsigned cc = lh[i];
        if (cc) atomicAdd(&hist[bh * 2048 + i], cc);
    }
}

// ---------------- select0: 2048-bin scan, one block per bh; resets hist --------
__global__ void k_select0(unsigned* __restrict__ hist, unsigned* __restrict__ prefix,
                          unsigned* __restrict__ krem) {
    int bh = blockIdx.x;
    unsigned* hrow = hist + bh * 2048;
    __shared__ unsigned ps[256];
    __shared__ unsigned sdig, sbelow;
    int tid = threadIdx.x;
    unsigned s = 0;
#pragma unroll
    for (int i = 0; i < 8; i++) s += hrow[tid * 8 + i];
    ps[tid] = s;
    __syncthreads();
    if (tid == 0) {
        unsigned k = KTH, run = 0; int chunk = 255;
        for (int t2 = 0; t2 < 256; t2++) {
            if (run + ps[t2] >= k) { chunk = t2; break; }
            run += ps[t2];
        }
        int d = 7;
        for (int i = 0; i < 8; i++) {
            unsigned v = hrow[chunk * 8 + i];
            if (run + v >= k) { d = i; break; }
            run += v;
        }
        sdig = (unsigned)(chunk * 8 + d); sbelow = run;
    }
    __syncthreads();
#pragma unroll
    for (int i = 0; i < 8; i++) hrow[tid * 8 + i] = 0u;
    if (tid == 0) { prefix[bh] = sdig; krem[bh] = KTH - sbelow; }
}

// ---------------- hist2: stream P, 32-bin hist among 11-bit-prefix matches -----
__global__ __launch_bounds__(256) void k_hist2(const ushort* __restrict__ P,
                                               const unsigned* __restrict__ prefix,
                                               unsigned* __restrict__ hist) {
    __shared__ unsigned lh[32];
    int tid = threadIdx.x;
    if (tid < 32) lh[tid] = 0u;
    __syncthreads();
    int bh = blockIdx.y;
    unsigned pm = prefix[bh];
    const ushort* pb = P + ((size_t)bh << 20) + (size_t)blockIdx.x * 16384;
#pragma unroll
    for (int it = 0; it < 8; it++) {
        uint4 v = *(const uint4*)(pb + it * 2048 + tid * 8);
        unsigned w[4] = {v.x, v.y, v.z, v.w};
#pragma unroll
        for (int e = 0; e < 4; e++) {
            unsigned lo = w[e] & 0xFFFFu, hi = w[e] >> 16;
            if ((lo >> 5) == pm) atomicAdd(&lh[lo & 31u], 1u);
            if ((hi >> 5) == pm) atomicAdd(&lh[hi & 31u], 1u);
        }
    }
    __syncthreads();
    if (tid < 32) {
        unsigned c = lh[tid];
        if (c) atomicAdd(&hist[bh * 2048 + tid], c);
    }
}

// ---------------- final select: 32 bins -> bf16 threshold bit pattern ----------
__global__ void k_selectF(const unsigned* __restrict__ hist,
                          const unsigned* __restrict__ prefix,
                          const unsigned* __restrict__ krem,
                          unsigned* __restrict__ thrb) {
    int bh = threadIdx.x;
    if (bh >= BH) return;
    const unsigned* hrow = hist + bh * 2048;
    unsigned k = krem[bh], run = 0;
    int d = 31;
    for (int i = 0; i < 32; i++) {
        unsigned c = hrow[i];
        if (run + c >= k) { d = i; break; }
        run += c;
    }
    thrb[bh] = (prefix[bh] << 5) | (unsigned)d;
}

// ---------------- PV: ctx = (masked P) @ Vh / rowsum ---------------------------
// grid (64, 48): 16 rows per block; 4 waves split the j-axis (256 each);
// LDS cross-wave reduction. Vl dropped (P already bf16-quantized).
__global__ __launch_bounds__(256) void k_pv(const ushort* __restrict__ P,
                                            const ushort* __restrict__ Vth,
                                            const unsigned* __restrict__ thrb,
                                            ushort* __restrict__ ctxh,
                                            ushort* __restrict__ ctxl) {
    __shared__ float sred[4 * 1280];   // [wave][ (acc_idx*4+r)*64 + lane ]
    int bh = blockIdx.y;
    int b = bh / NHEADS, h = bh % NHEADS;
    int lane = threadIdx.x & 63, wave = threadIdx.x >> 6;
    int l15 = lane & 15, q = lane >> 4;
    int ibase = blockIdx.x * 16;
    unsigned t = thrb[bh];
    const ushort* prow = P + ((size_t)bh << 20) + (size_t)(ibase + l15) * 1024 + q * 8;
    const ushort* vh0 = Vth + ((size_t)bh << 16);   // [64][1024]
    f32x4 acc[4] = {};
    f32x4 lacc = {};
    uint4 onesu = {0x3F803F80u, 0x3F803F80u, 0x3F803F80u, 0x3F803F80u};
    bf16x8 ones = *(bf16x8*)&onesu;
    int jw = wave * 256;
#pragma unroll 2
    for (int j0 = jw; j0 < jw + 256; j0 += 32) {
        uint4 a = *(const uint4*)(prow + j0);
        unsigned* w = (unsigned*)&a;
#pragma unroll
        for (int e = 0; e < 4; e++) {
            unsigned lo = w[e] & 0xFFFFu, hi = w[e] >> 16;
            lo = (lo <= t) ? 0u : lo;
            hi = (hi <= t) ? 0u : hi;
            w[e] = lo | (hi << 16);
        }
        bf16x8 pa = *(bf16x8*)&a;
#pragma unroll
        for (int nt = 0; nt < 4; nt++) {
            size_t off = (size_t)(nt * 16 + l15) * 1024 + j0 + q * 8;
            bf16x8 fvh = *(const bf16x8*)(vh0 + off);
            acc[nt] = __builtin_amdgcn_mfma_f32_16x16x32_bf16(pa, fvh, acc[nt], 0, 0, 0);
        }
        lacc = __builtin_amdgcn_mfma_f32_16x16x32_bf16(pa, ones, lacc, 0, 0, 0);
    }
    // cross-wave reduce: partial sums over j-quarters
    float* my = sred + wave * 1280;
#pragma unroll
    for (int nt = 0; nt < 4; nt++)
#pragma unroll
        for (int r = 0; r < 4; r++)
            my[(nt * 4 + r) * 64 + lane] = acc[nt][r];
#pragma unroll
    for (int r = 0; r < 4; r++)
        my[(16 + r) * 64 + lane] = lacc[r];
    __syncthreads();
    for (int f = threadIdx.x; f < 1280; f += 256)
        sred[f] = sred[f] + sred[1280 + f] + sred[2560 + f] + sred[3840 + f];
    __syncthreads();
    // epilogue: wave w handles d-group nt=w; rows i = ibase + q*4 + r
#pragma unroll
    for (int r = 0; r < 4; r++) {
        int i = ibase + q * 4 + r;
        float l = sred[(16 + r) * 64 + lane];
        float v = sred[(wave * 4 + r) * 64 + lane];
        int d = wave * 16 + l15;
        ushort hs, ls;
        split1(v / l, hs, ls);
        size_t off = ((size_t)(b * SEQ + i)) * DMODEL + h * 64 + d;
        ctxh[off] = hs;
        ctxl[off] = ls;
    }
}

extern "C" void kernel_launch(void* const* d_in, const int* in_sizes, int n_in,
                              void* d_out, int out_size, void* d_ws, size_t ws_size,
                              hipStream_t stream) {
    const float* x    = (const float*)d_in[0];
    const float* Wqkv = (const float*)d_in[1];
    const float* bqkv = (const float*)d_in[2];
    const float* Wout = (const float*)d_in[3];
    const float* bout = (const float*)d_in[4];
    float* out = (float*)d_out;

    char* ws = (char*)d_ws;
    // persistent layout
    ushort* Qh  = (ushort*)(ws + 0);                 //  6,291,456
    ushort* Ql  = (ushort*)(ws + 6291456);
    ushort* Kh  = (ushort*)(ws + 12582912);
    ushort* Kl  = (ushort*)(ws + 18874368);
    ushort* Vth = (ushort*)(ws + 25165824);          //  6,291,456 (hi only)
    ushort* P   = (ushort*)(ws + 37748736);          // 100,663,296 -> ends 138,412,032
    ushort* ctxh = (ushort*)(ws + 239075328);        //  6,291,456
    ushort* ctxl = (ushort*)(ws + 245366784);        // ends 251,658,240
    unsigned* hist   = (unsigned*)(ws + 251658240);  // 393,216
    unsigned* prefix = (unsigned*)(ws + 252051456);  // 192
    unsigned* krem   = (unsigned*)(ws + 252051648);  // 192
    unsigned* thrb   = (unsigned*)(ws + 252051840);  // 192
    // overlays inside P region (dead until k_scores writes P):
    ushort* xh     = (ushort*)(ws + 37748736);
    ushort* xl     = (ushort*)(ws + 37748736 + 6291456);
    ushort* Wqkvth = (ushort*)(ws + 37748736 + 12582912);
    ushort* Wqkvtl = (ushort*)(ws + 37748736 + 16121856);
    // Wout split overlays P (dead after k_pv):
    ushort* Woutth = (ushort*)(ws + 37748736);
    ushort* Wouttl = (ushort*)(ws + 37748736 + 1179648);

    k_init<<<384, 256, 0, stream>>>(hist);
    k_xsplit<<<NTOK * DMODEL / 1024, 256, 0, stream>>>(x, xh, xl, NTOK * DMODEL);
    k_wsplit<<<dim3(D3 / 64, DMODEL / 64), 256, 0, stream>>>(Wqkv, Wqkvth, Wqkvtl, DMODEL, D3);
    k_gemm_qkv<<<dim3(D3 / 128, NTOK / 128), 256, 0, stream>>>(
        xh, xl, Wqkvth, Wqkvtl, bqkv, Qh, Ql, Kh, Kl, Vth);
    // P = bf16(exp(QK^T/8)) + fused 11-bit histogram
    k_scores<<<dim3(8, 8, BH), 256, 0, stream>>>(Qh, Ql, Kh, Kl, P, hist);
    k_select0<<<BH, 256, 0, stream>>>(hist, prefix, krem);
    // exact bf16 threshold: one streaming pass, 32-bin
    k_hist2<<<dim3(64, BH), 256, 0, stream>>>(P, prefix, hist);
    k_selectF<<<1, 64, 0, stream>>>(hist, prefix, krem, thrb);
    // ctx = masked-softmax(P) @ V
    k_pv<<<dim3(64, BH), 256, 0, stream>>>(P, Vth, thrb, ctxh, ctxl);
    // out = ctx @ W_out + b_out
    k_wsplit<<<dim3(DMODEL / 64, DMODEL / 64), 256, 0, stream>>>(Wout, Woutth, Wouttl, DMODEL, DMODEL);
    k_gemm_mfma<<<dim3(DMODEL / 128, NTOK / 128), 256, 0, stream>>>(
        ctxh, ctxl, Woutth, Wouttl, bout, out, NTOK, DMODEL, DMODEL);
}

// Round 6
// 327.182 us; speedup vs baseline: 2.5307x; 1.0821x over previous
//
#include <hip/hip_runtime.h>
#include <math.h>

#define SEQ 1024
#define DMODEL 768
#define NHEADS 12
#define HDIM 64
#define D3 2304
#define BH 48            // BATCH*NHEADS
#define NTOK 4096        // BATCH*SEQ
#define NN (SEQ*SEQ)     // 1048576
#define KTH 104857u      // int(1024*1024*0.1)

typedef __bf16 bf16x8 __attribute__((ext_vector_type(8)));
typedef float  f32x4  __attribute__((ext_vector_type(4)));

// swizzled LDS offset (ushort units): row stride 32, 16B chunk XOR'd to kill
// bank conflicts without padding (2-way max on read & write)
#define SWZ(row, chunk) ((row) * 32 + (((chunk) ^ (((row) >> 1) & 3)) * 8))

// ---------------- fp32 -> (bf16 hi, bf16 lo) split, RNE ----------------
__device__ __forceinline__ void split1(float x, ushort& h, ushort& l) {
    unsigned b  = __float_as_uint(x);
    unsigned hb = (b + 0x7FFFu + ((b >> 16) & 1u)) >> 16;   // RNE to bf16
    float hf = __uint_as_float(hb << 16);
    float r  = x - hf;
    unsigned rb = __float_as_uint(r);
    unsigned lb = (rb + 0x7FFFu + ((rb >> 16) & 1u)) >> 16;
    h = (ushort)hb; l = (ushort)lb;
}

__device__ __forceinline__ ushort bf16rne(float x) {
    unsigned b = __float_as_uint(x);
    return (ushort)((b + 0x7FFFu + ((b >> 16) & 1u)) >> 16);
}

// ---------------- elementwise split: x -> xh, xl (+ zero hist) ----------------
__global__ __launch_bounds__(256) void k_xsplit(const float* __restrict__ x,
                                                ushort* __restrict__ xh,
                                                ushort* __restrict__ xl, int n,
                                                unsigned* __restrict__ hist) {
    int g = blockIdx.x * 256 + threadIdx.x;
    if (g < BH * 2048) hist[g] = 0u;
    int i = g * 4;
    if (i >= n) return;
    float4 v = *(const float4*)(x + i);
    ushort4 h, l;
    split1(v.x, h.x, l.x); split1(v.y, h.y, l.y);
    split1(v.z, h.z, l.z); split1(v.w, h.w, l.w);
    *(ushort4*)(xh + i) = h;
    *(ushort4*)(xl + i) = l;
}

// ---------------- transpose + split: W[K][N] -> Wt_h/Wt_l [N][K] ----------------
__global__ __launch_bounds__(256) void k_wsplit(const float* __restrict__ W,
                                                ushort* __restrict__ Wth,
                                                ushort* __restrict__ Wtl,
                                                int K, int N) {
    __shared__ float t[64][65];
    int k0 = blockIdx.y * 64, n0 = blockIdx.x * 64;
    int tid = threadIdx.x;
    int r = tid >> 4, c = (tid & 15) * 4;
#pragma unroll
    for (int u = 0; u < 4; u++) {
        int rr = r + u * 16;
        float4 v = *(const float4*)(W + (size_t)(k0 + rr) * N + n0 + c);
        t[rr][c] = v.x; t[rr][c + 1] = v.y; t[rr][c + 2] = v.z; t[rr][c + 3] = v.w;
    }
    __syncthreads();
    int n = tid >> 2, kc = (tid & 3) * 16;
    ushort hb[16] __attribute__((aligned(16)));
    ushort lb[16] __attribute__((aligned(16)));
#pragma unroll
    for (int j = 0; j < 16; j++) split1(t[kc + j][n], hb[j], lb[j]);
    ushort* dh = Wth + (size_t)(n0 + n) * K + k0 + kc;
    ushort* dl = Wtl + (size_t)(n0 + n) * K + k0 + kc;
    *(uint4*)(dh)     = *(uint4*)&hb[0];
    *(uint4*)(dh + 8) = *(uint4*)&hb[8];
    *(uint4*)(dl)     = *(uint4*)&lb[0];
    *(uint4*)(dl + 8) = *(uint4*)&lb[8];
}

// ======================================================================
// Pipelined bf16x3 GEMM core: BM=64, BN=128, BK=32, 256 thr.
// 4 waves in 2x2: wave computes 32x64 (mt2 x nt4 of 16x16).
// LDS double-buffered, XOR-swizzled (no padding). One barrier/iter;
// global loads for iter k+1 issue before iter k's MFMAs.
// ======================================================================
#define GEMM_CORE_SETUP(Kdim)                                                   \
    __shared__ ushort sA[2][2][64 * 32];                                        \
    __shared__ ushort sB[2][2][128 * 32];                                       \
    int tid = threadIdx.x, lane = tid & 63, wave = tid >> 6;                    \
    int wm = (wave >> 1) * 32, wn = (wave & 1) * 64;                            \
    int l15 = lane & 15, q = lane >> 4;                                         \
    int sr = tid >> 2, sc = tid & 3;                                            \
    const int K = (Kdim);                                                       \
    const ushort* pAh = Ah + (size_t)(m0 + sr) * K + sc * 8;                    \
    const ushort* pAl = Al + (size_t)(m0 + sr) * K + sc * 8;                    \
    const ushort* pBh = Bh + (size_t)(n0 + sr) * K + sc * 8;                    \
    const ushort* pBl = Bl + (size_t)(n0 + sr) * K + sc * 8;                    \
    size_t bstep = (size_t)64 * K;                                              \
    int wA = SWZ(sr, sc), wB2 = SWZ(sr + 64, sc);                               \
    f32x4 acc[2][4] = {};                                                       \
    uint4 rAh = *(const uint4*)(pAh);                                           \
    uint4 rAl = *(const uint4*)(pAl);                                           \
    uint4 rBh0 = *(const uint4*)(pBh);                                          \
    uint4 rBh1 = *(const uint4*)(pBh + bstep);                                  \
    uint4 rBl0 = *(const uint4*)(pBl);                                          \
    uint4 rBl1 = *(const uint4*)(pBl + bstep);                                  \
    *(uint4*)(&sA[0][0][wA])  = rAh;                                            \
    *(uint4*)(&sA[0][1][wA])  = rAl;                                            \
    *(uint4*)(&sB[0][0][wA])  = rBh0;                                           \
    *(uint4*)(&sB[0][0][wB2]) = rBh1;                                           \
    *(uint4*)(&sB[0][1][wA])  = rBl0;                                           \
    *(uint4*)(&sB[0][1][wB2]) = rBl1;                                           \
    __syncthreads();                                                            \
    const int NIT = K / 32;                                                     \
    for (int it = 0; it < NIT; ++it) {                                          \
        int cur = it & 1;                                                       \
        if (it + 1 < NIT) {                                                     \
            int ko = (it + 1) * 32;                                             \
            rAh  = *(const uint4*)(pAh + ko);                                   \
            rAl  = *(const uint4*)(pAl + ko);                                   \
            rBh0 = *(const uint4*)(pBh + ko);                                   \
            rBh1 = *(const uint4*)(pBh + bstep + ko);                           \
            rBl0 = *(const uint4*)(pBl + ko);                                   \
            rBl1 = *(const uint4*)(pBl + bstep + ko);                           \
        }                                                                       \
        bf16x8 fah[2], fal[2], fbh[4], fbl[4];                                  \
        _Pragma("unroll")                                                       \
        for (int mt = 0; mt < 2; mt++) {                                        \
            int rr = wm + mt * 16 + l15;                                        \
            fah[mt] = *(const bf16x8*)(&sA[cur][0][SWZ(rr, q)]);                \
            fal[mt] = *(const bf16x8*)(&sA[cur][1][SWZ(rr, q)]);                \
        }                                                                       \
        _Pragma("unroll")                                                       \
        for (int nt = 0; nt < 4; nt++) {                                        \
            int rr = wn + nt * 16 + l15;                                        \
            fbh[nt] = *(const bf16x8*)(&sB[cur][0][SWZ(rr, q)]);                \
            fbl[nt] = *(const bf16x8*)(&sB[cur][1][SWZ(rr, q)]);                \
        }                                                                       \
        _Pragma("unroll")                                                       \
        for (int mt = 0; mt < 2; mt++)                                          \
            _Pragma("unroll")                                                   \
            for (int nt = 0; nt < 4; nt++) {                                    \
                acc[mt][nt] = __builtin_amdgcn_mfma_f32_16x16x32_bf16(          \
                    fah[mt], fbh[nt], acc[mt][nt], 0, 0, 0);                    \
                acc[mt][nt] = __builtin_amdgcn_mfma_f32_16x16x32_bf16(          \
                    fah[mt], fbl[nt], acc[mt][nt], 0, 0, 0);                    \
                acc[mt][nt] = __builtin_amdgcn_mfma_f32_16x16x32_bf16(          \
                    fal[mt], fbh[nt], acc[mt][nt], 0, 0, 0);                    \
            }                                                                   \
        if (it + 1 < NIT) {                                                     \
            int nxt = cur ^ 1;                                                  \
            *(uint4*)(&sA[nxt][0][wA])  = rAh;                                  \
            *(uint4*)(&sA[nxt][1][wA])  = rAl;                                  \
            *(uint4*)(&sB[nxt][0][wA])  = rBh0;                                 \
            *(uint4*)(&sB[nxt][0][wB2]) = rBh1;                                 \
            *(uint4*)(&sB[nxt][1][wA])  = rBl0;                                 \
            *(uint4*)(&sB[nxt][1][wB2]) = rBl1;                                 \
        }                                                                       \
        __syncthreads();                                                        \
    }

// ---------------- out-proj GEMM: C = A@B + bias (fp32 out) ----------------
// grid (N/128, M/64)
__global__ __launch_bounds__(256) void k_gemm_out(
    const ushort* __restrict__ Ah, const ushort* __restrict__ Al,
    const ushort* __restrict__ Bh, const ushort* __restrict__ Bl,
    const float* __restrict__ bias, float* __restrict__ C,
    int M, int N, int Kin) {
    int m0 = blockIdx.y * 64, n0 = blockIdx.x * 128;
    GEMM_CORE_SETUP(Kin)
#pragma unroll
    for (int nt = 0; nt < 4; nt++) {
        int col = n0 + wn + nt * 16 + l15;
        float bv = bias[col];
#pragma unroll
        for (int mt = 0; mt < 2; mt++) {
            int rowb = m0 + wm + mt * 16 + q * 4;
#pragma unroll
            for (int r = 0; r < 4; r++)
                C[(size_t)(rowb + r) * N + col] = acc[mt][nt][r] + bv;
        }
    }
}

// ---------------- QKV GEMM: epilogue writes split Q/K straight + V(hi) transposed
// grid (D3/128, NTOK/64)
__global__ __launch_bounds__(256) void k_gemm_qkv(
    const ushort* __restrict__ Ah, const ushort* __restrict__ Al,
    const ushort* __restrict__ Bh, const ushort* __restrict__ Bl,
    const float* __restrict__ bias,
    ushort* __restrict__ Qh, ushort* __restrict__ Ql,
    ushort* __restrict__ Kh, ushort* __restrict__ Kl,
    ushort* __restrict__ Vth) {
    int m0 = blockIdx.y * 64, n0 = blockIdx.x * 128;
    GEMM_CORE_SETUP(DMODEL)
    int region = n0 / 768;    // 0=Q, 1=K, 2=V (uniform per block: 128 | 768)
#pragma unroll
    for (int nt = 0; nt < 4; nt++) {
        int col = n0 + wn + nt * 16 + l15;
        float bv = bias[col];
        int cin = col - region * 768;
        int h = cin >> 6, d = cin & 63;
#pragma unroll
        for (int mt = 0; mt < 2; mt++) {
            int rowb = m0 + wm + mt * 16 + q * 4;
            int b = rowb >> 10;
            int s0 = rowb & 1023;
            int bh = b * NHEADS + h;
            if (region == 2) {
                ushort h4[4] __attribute__((aligned(8)));
#pragma unroll
                for (int r = 0; r < 4; r++)
                    h4[r] = bf16rne(acc[mt][nt][r] + bv);
                size_t off = ((size_t)(bh * 64 + d) << 10) + s0;
                *(ushort4*)(Vth + off) = *(ushort4*)h4;
            } else {
                ushort* Ph = region ? Kh : Qh;
                ushort* Pl = region ? Kl : Ql;
                size_t off = ((size_t)((bh << 10) + s0)) * 64 + d;
#pragma unroll
                for (int r = 0; r < 4; r++) {
                    ushort hs, ls;
                    split1(acc[mt][nt][r] + bv, hs, ls);
                    Ph[off + (size_t)r * 64] = hs;
                    Pl[off + (size_t)r * 64] = ls;
                }
            }
        }
    }
}

// ---------------- scores: P[bh,i,j] = bf16(exp(q_i.k_j/8)) + 11-bit hist -------
// grid (8, 8, 48). Direct-global Q/K fragments; LDS used for P transpose + hist.
__global__ __launch_bounds__(256) void k_scores(
    const ushort* __restrict__ Qh, const ushort* __restrict__ Ql,
    const ushort* __restrict__ Kh, const ushort* __restrict__ Kl,
    ushort* __restrict__ P, unsigned* __restrict__ hist) {
    __shared__ ushort sP[128 * 132];
    __shared__ unsigned lh[2048];
    int bh = blockIdx.z;
    int i0 = blockIdx.y * 128, j0 = blockIdx.x * 128;
    int tid = threadIdx.x, lane = tid & 63, wave = tid >> 6;
    int l15 = lane & 15, q = lane >> 4;
    int wm = (wave >> 1) * 64, wn = (wave & 1) * 64;
    for (int i = tid; i < 2048; i += 256) lh[i] = 0u;

    const ushort* qb  = Qh + (((size_t)bh << 10)) * 64;
    const ushort* qlb = Ql + (((size_t)bh << 10)) * 64;
    const ushort* kb  = Kh + (((size_t)bh << 10)) * 64;
    const ushort* klb = Kl + (((size_t)bh << 10)) * 64;

    f32x4 acc[4][4] = {};
#pragma unroll
    for (int kk = 0; kk < 64; kk += 32) {
        bf16x8 fqh[4], fql[4], fkh[4], fkl[4];
#pragma unroll
        for (int mt = 0; mt < 4; mt++) {
            size_t off = (size_t)(i0 + wm + mt * 16 + l15) * 64 + kk + q * 8;
            fqh[mt] = *(const bf16x8*)(qb + off);
            fql[mt] = *(const bf16x8*)(qlb + off);
        }
#pragma unroll
        for (int nt = 0; nt < 4; nt++) {
            size_t off = (size_t)(j0 + wn + nt * 16 + l15) * 64 + kk + q * 8;
            fkh[nt] = *(const bf16x8*)(kb + off);
            fkl[nt] = *(const bf16x8*)(klb + off);
        }
#pragma unroll
        for (int mt = 0; mt < 4; mt++)
#pragma unroll
            for (int nt = 0; nt < 4; nt++) {
                acc[mt][nt] = __builtin_amdgcn_mfma_f32_16x16x32_bf16(
                    fqh[mt], fkh[nt], acc[mt][nt], 0, 0, 0);
                acc[mt][nt] = __builtin_amdgcn_mfma_f32_16x16x32_bf16(
                    fqh[mt], fkl[nt], acc[mt][nt], 0, 0, 0);
                acc[mt][nt] = __builtin_amdgcn_mfma_f32_16x16x32_bf16(
                    fql[mt], fkh[nt], acc[mt][nt], 0, 0, 0);
            }
    }
    __syncthreads();   // lh zeroed by all
#pragma unroll
    for (int mt = 0; mt < 4; mt++)
#pragma unroll
        for (int nt = 0; nt < 4; nt++) {
            int jj = wn + nt * 16 + l15;
            int ib = wm + mt * 16 + q * 4;
#pragma unroll
            for (int r2 = 0; r2 < 4; r2++) {
                ushort pb = bf16rne(__expf(acc[mt][nt][r2] * 0.125f));
                sP[(ib + r2) * 132 + jj] = pb;
                atomicAdd(&lh[pb >> 5], 1u);
            }
        }
    __syncthreads();
    int rloc = tid >> 1;
    int ch = (tid & 1) * 64;
    ushort* dst = P + ((size_t)bh << 20) + (size_t)(i0 + rloc) * 1024 + j0 + ch;
    const ushort* src = sP + rloc * 132 + ch;
#pragma unroll
    for (int c = 0; c < 8; c++)
        *(uint4*)(dst + c * 8) = *(const uint4*)(src + c * 8);
    for (int i = tid; i < 2048; i += 256) {
        unsigned cc = lh[i];
        if (cc) atomicAdd(&hist[bh * 2048 + i], cc);
    }
}

// ---------------- select0: 2048-bin scan, one block per bh; resets hist --------
__global__ void k_select0(unsigned* __restrict__ hist, unsigned* __restrict__ prefix,
                          unsigned* __restrict__ krem) {
    int bh = blockIdx.x;
    unsigned* hrow = hist + bh * 2048;
    __shared__ unsigned ps[256];
    __shared__ unsigned sdig, sbelow;
    int tid = threadIdx.x;
    unsigned s = 0;
#pragma unroll
    for (int i = 0; i < 8; i++) s += hrow[tid * 8 + i];
    ps[tid] = s;
    __syncthreads();
    if (tid == 0) {
        unsigned k = KTH, run = 0; int chunk = 255;
        for (int t2 = 0; t2 < 256; t2++) {
            if (run + ps[t2] >= k) { chunk = t2; break; }
            run += ps[t2];
        }
        int d = 7;
        for (int i = 0; i < 8; i++) {
            unsigned v = hrow[chunk * 8 + i];
            if (run + v >= k) { d = i; break; }
            run += v;
        }
        sdig = (unsigned)(chunk * 8 + d); sbelow = run;
    }
    __syncthreads();
#pragma unroll
    for (int i = 0; i < 8; i++) hrow[tid * 8 + i] = 0u;
    if (tid == 0) { prefix[bh] = sdig; krem[bh] = KTH - sbelow; }
}

// ---------------- hist2: stream P, 32-bin hist among 11-bit-prefix matches -----
__global__ __launch_bounds__(256) void k_hist2(const ushort* __restrict__ P,
                                               const unsigned* __restrict__ prefix,
                                               unsigned* __restrict__ hist) {
    __shared__ unsigned lh[32];
    int tid = threadIdx.x;
    if (tid < 32) lh[tid] = 0u;
    __syncthreads();
    int bh = blockIdx.y;
    unsigned pm = prefix[bh];
    const ushort* pb = P + ((size_t)bh << 20) + (size_t)blockIdx.x * 16384;
#pragma unroll
    for (int it = 0; it < 8; it++) {
        uint4 v = *(const uint4*)(pb + it * 2048 + tid * 8);
        unsigned w[4] = {v.x, v.y, v.z, v.w};
#pragma unroll
        for (int e = 0; e < 4; e++) {
            unsigned lo = w[e] & 0xFFFFu, hi = w[e] >> 16;
            if ((lo >> 5) == pm) atomicAdd(&lh[lo & 31u], 1u);
            if ((hi >> 5) == pm) atomicAdd(&lh[hi & 31u], 1u);
        }
    }
    __syncthreads();
    if (tid < 32) {
        unsigned c = lh[tid];
        if (c) atomicAdd(&hist[bh * 2048 + tid], c);
    }
}

// ---------------- final select: 32 bins -> bf16 threshold bit pattern ----------
__global__ void k_selectF(const unsigned* __restrict__ hist,
                          const unsigned* __restrict__ prefix,
                          const unsigned* __restrict__ krem,
                          unsigned* __restrict__ thrb) {
    int bh = threadIdx.x;
    if (bh >= BH) return;
    const unsigned* hrow = hist + bh * 2048;
    unsigned k = krem[bh], run = 0;
    int d = 31;
    for (int i = 0; i < 32; i++) {
        unsigned c = hrow[i];
        if (run + c >= k) { d = i; break; }
        run += c;
    }
    thrb[bh] = (prefix[bh] << 5) | (unsigned)d;
}

// ---------------- PV: ctx = (masked P) @ Vh / rowsum ---------------------------
// grid (64, 48): 16 rows per block; 4 waves split the j-axis (256 each);
// LDS cross-wave reduction.
__global__ __launch_bounds__(256) void k_pv(const ushort* __restrict__ P,
                                            const ushort* __restrict__ Vth,
                                            const unsigned* __restrict__ thrb,
                                            ushort* __restrict__ ctxh,
                                            ushort* __restrict__ ctxl) {
    __shared__ float sred[4 * 1280];   // [wave][ (acc_idx*4+r)*64 + lane ]
    int bh = blockIdx.y;
    int b = bh / NHEADS, h = bh % NHEADS;
    int lane = threadIdx.x & 63, wave = threadIdx.x >> 6;
    int l15 = lane & 15, q = lane >> 4;
    int ibase = blockIdx.x * 16;
    unsigned t = thrb[bh];
    const ushort* prow = P + ((size_t)bh << 20) + (size_t)(ibase + l15) * 1024 + q * 8;
    const ushort* vh0 = Vth + ((size_t)bh << 16);   // [64][1024]
    f32x4 acc[4] = {};
    f32x4 lacc = {};
    uint4 onesu = {0x3F803F80u, 0x3F803F80u, 0x3F803F80u, 0x3F803F80u};
    bf16x8 ones = *(bf16x8*)&onesu;
    int jw = wave * 256;
#pragma unroll 2
    for (int j0 = jw; j0 < jw + 256; j0 += 32) {
        uint4 a = *(const uint4*)(prow + j0);
        unsigned* w = (unsigned*)&a;
#pragma unroll
        for (int e = 0; e < 4; e++) {
            unsigned lo = w[e] & 0xFFFFu, hi = w[e] >> 16;
            lo = (lo <= t) ? 0u : lo;
            hi = (hi <= t) ? 0u : hi;
            w[e] = lo | (hi << 16);
        }
        bf16x8 pa = *(bf16x8*)&a;
#pragma unroll
        for (int nt = 0; nt < 4; nt++) {
            size_t off = (size_t)(nt * 16 + l15) * 1024 + j0 + q * 8;
            bf16x8 fvh = *(const bf16x8*)(vh0 + off);
            acc[nt] = __builtin_amdgcn_mfma_f32_16x16x32_bf16(pa, fvh, acc[nt], 0, 0, 0);
        }
        lacc = __builtin_amdgcn_mfma_f32_16x16x32_bf16(pa, ones, lacc, 0, 0, 0);
    }
    float* my = sred + wave * 1280;
#pragma unroll
    for (int nt = 0; nt < 4; nt++)
#pragma unroll
        for (int r = 0; r < 4; r++)
            my[(nt * 4 + r) * 64 + lane] = acc[nt][r];
#pragma unroll
    for (int r = 0; r < 4; r++)
        my[(16 + r) * 64 + lane] = lacc[r];
    __syncthreads();
    for (int f = threadIdx.x; f < 1280; f += 256)
        sred[f] = sred[f] + sred[1280 + f] + sred[2560 + f] + sred[3840 + f];
    __syncthreads();
#pragma unroll
    for (int r = 0; r < 4; r++) {
        int i = ibase + q * 4 + r;
        float l = sred[(16 + r) * 64 + lane];
        float v = sred[(wave * 4 + r) * 64 + lane];
        int d = wave * 16 + l15;
        ushort hs, ls;
        split1(v / l, hs, ls);
        size_t off = ((size_t)(b * SEQ + i)) * DMODEL + h * 64 + d;
        ctxh[off] = hs;
        ctxl[off] = ls;
    }
}

extern "C" void kernel_launch(void* const* d_in, const int* in_sizes, int n_in,
                              void* d_out, int out_size, void* d_ws, size_t ws_size,
                              hipStream_t stream) {
    const float* x    = (const float*)d_in[0];
    const float* Wqkv = (const float*)d_in[1];
    const float* bqkv = (const float*)d_in[2];
    const float* Wout = (const float*)d_in[3];
    const float* bout = (const float*)d_in[4];
    float* out = (float*)d_out;

    char* ws = (char*)d_ws;
    // persistent layout
    ushort* Qh  = (ushort*)(ws + 0);                 //  6,291,456
    ushort* Ql  = (ushort*)(ws + 6291456);
    ushort* Kh  = (ushort*)(ws + 12582912);
    ushort* Kl  = (ushort*)(ws + 18874368);
    ushort* Vth = (ushort*)(ws + 25165824);          //  6,291,456 (hi only)
    ushort* P   = (ushort*)(ws + 37748736);          // 100,663,296 -> ends 138,412,032
    ushort* ctxh = (ushort*)(ws + 239075328);        //  6,291,456
    ushort* ctxl = (ushort*)(ws + 245366784);        // ends 251,658,240
    unsigned* hist   = (unsigned*)(ws + 251658240);  // 393,216
    unsigned* prefix = (unsigned*)(ws + 252051456);  // 192
    unsigned* krem   = (unsigned*)(ws + 252051648);  // 192
    unsigned* thrb   = (unsigned*)(ws + 252051840);  // 192
    // overlays inside P region (dead until k_scores writes P):
    ushort* xh     = (ushort*)(ws + 37748736);
    ushort* xl     = (ushort*)(ws + 37748736 + 6291456);
    ushort* Wqkvth = (ushort*)(ws + 37748736 + 12582912);
    ushort* Wqkvtl = (ushort*)(ws + 37748736 + 16121856);
    // Wout split overlays P (dead after k_pv):
    ushort* Woutth = (ushort*)(ws + 37748736);
    ushort* Wouttl = (ushort*)(ws + 37748736 + 1179648);

    k_xsplit<<<NTOK * DMODEL / 1024, 256, 0, stream>>>(x, xh, xl, NTOK * DMODEL, hist);
    k_wsplit<<<dim3(D3 / 64, DMODEL / 64), 256, 0, stream>>>(Wqkv, Wqkvth, Wqkvtl, DMODEL, D3);
    k_gemm_qkv<<<dim3(D3 / 128, NTOK / 64), 256, 0, stream>>>(
        xh, xl, Wqkvth, Wqkvtl, bqkv, Qh, Ql, Kh, Kl, Vth);
    // P = bf16(exp(QK^T/8)) + fused 11-bit histogram
    k_scores<<<dim3(8, 8, BH), 256, 0, stream>>>(Qh, Ql, Kh, Kl, P, hist);
    k_select0<<<BH, 256, 0, stream>>>(hist, prefix, krem);
    // exact bf16 threshold: one streaming pass, 32-bin
    k_hist2<<<dim3(64, BH), 256, 0, stream>>>(P, prefix, hist);
    k_selectF<<<1, 64, 0, stream>>>(hist, prefix, krem, thrb);
    // ctx = masked-softmax(P) @ V
    k_pv<<<dim3(64, BH), 256, 0, stream>>>(P, Vth, thrb, ctxh, ctxl);
    // out = ctx @ W_out + b_out
    k_wsplit<<<dim3(DMODEL / 64, DMODEL / 64), 256, 0, stream>>>(Wout, Woutth, Wouttl, DMODEL, DMODEL);
    k_gemm_out<<<dim3(DMODEL / 128, NTOK / 64), 256, 0, stream>>>(
        ctxh, ctxl, Woutth, Wouttl, bout, out, NTOK, DMODEL, DMODEL);
}